// Round 7
// baseline (375.257 us; speedup 1.0000x reference)
//
#include <hip/hip_runtime.h>
#include <cstdint>
#include <cmath>

typedef unsigned short u16;
typedef __attribute__((ext_vector_type(4))) float f32x4;
typedef __attribute__((ext_vector_type(8))) short bf16x8;

#define D_MODEL 1024
#define SEQ     2048
#define BATCH   4
#define NHEAD   16
#define MTOT    (BATCH*SEQ)      /* 8192 rows */
#define NXE     ((size_t)MTOT * D_MODEL)   /* 8,388,608 elems per plane */

static_assert(sizeof(bf16x8) == 16, "frag size");

__device__ __forceinline__ float bf2f(u16 u) {
    union { uint32_t i; float f; } v; v.i = ((uint32_t)u) << 16; return v.f;
}
__device__ __forceinline__ u16 f2bf(float x) {
    union { float f; uint32_t i; } v; v.f = x;
    uint32_t r = (v.i + 0x7FFFu + ((v.i >> 16) & 1u)) >> 16;   // RNE
    return (u16)r;
}
__device__ __forceinline__ u16 f2bf_trunc(float x) {          // cheap: P only
    union { float f; uint32_t i; } v; v.f = x;
    return (u16)(v.i >> 16);
}

// exp2 that lowers to a bare v_exp_f32 (HIP has no __exp2f; glibc macro clash)
#if defined(__has_builtin)
#if __has_builtin(__builtin_amdgcn_exp2f)
#define EXP2_FAST(x) __builtin_amdgcn_exp2f(x)
#endif
#endif
#ifndef EXP2_FAST
#define EXP2_FAST(x) exp2f(x)
#endif

typedef const __attribute__((address_space(1))) void* gptr_t;
typedef __attribute__((address_space(3))) void* sptr_t;
__device__ __forceinline__ void gload_lds16(const void* g, void* l) {
    __builtin_amdgcn_global_load_lds((gptr_t)g, (sptr_t)l, 16, 0, 0);
}

// extract u16 element e (compile-time const after unroll) from a uint4
__device__ __forceinline__ u16 u4get(const uint4& v, int e) {
    const uint32_t w = ((e >> 1) == 0) ? v.x : ((e >> 1) == 1) ? v.y
                     : ((e >> 1) == 2) ? v.z : v.w;
    return (u16)((e & 1) ? (w >> 16) : (w & 0xFFFFu));
}

// ---------------------------------------------------------------------------
// Precondition-failure flood: d_out is fp32; absmax report encodes 2^e.
// ---------------------------------------------------------------------------
__global__ __launch_bounds__(256) void diag_write(float* __restrict__ out, float v) {
    size_t i = (size_t)blockIdx.x * 256 + threadIdx.x;
    for (; i < NXE; i += (size_t)gridDim.x * 256) out[i] = v;
}

// ---------------------------------------------------------------------------
// Dtype sniffer (validated r3/r5/r6: inputs are fp32 -> flag=0).
// ---------------------------------------------------------------------------
__global__ void detect_dtype(const u16* __restrict__ x, int* __restrict__ flag) {
    __shared__ int cnt;
    if (threadIdx.x == 0) cnt = 0;
    __syncthreads();
    int c = 0;
#pragma unroll
    for (int k = 0; k < 16; ++k) {
        u16 e = x[2 * (threadIdx.x * 16 + k)];
        int ex = (e >> 7) & 0xFF;
        if (e == 0 || (ex >= 100 && ex <= 140)) ++c;
    }
    atomicAdd(&cnt, c);
    __syncthreads();
    if (threadIdx.x == 0) *flag = (cnt >= 3500) ? 1 : 0;
}

// ---------------------------------------------------------------------------
// Normalize inputs to bf16 planes (fp32 -> RNE downconvert; bf16 -> copy).
// ---------------------------------------------------------------------------
struct CvtArgs { const void* src[9]; u16* dst[9]; int n[9]; };

__global__ __launch_bounds__(256) void cvt_all(CvtArgs a, const int* __restrict__ flag) {
    const int seg = blockIdx.y;
    const int n = a.n[seg];
    const int i = (blockIdx.x * 256 + threadIdx.x) * 8;
    if (i >= n) return;
    u16* d = a.dst[seg] + i;
    if (*flag) {
        *(uint4*)d = *(const uint4*)((const u16*)a.src[seg] + i);
    } else {
        const float* s = (const float*)a.src[seg] + i;
        u16 tmp[8];
#pragma unroll
        for (int k = 0; k < 8; ++k) tmp[k] = f2bf(s[k]);
        *(uint4*)d = *(uint4*)tmp;
    }
}

// ---------------------------------------------------------------------------
// MFMA GEMM (m97 structure, 128x128, BK=32) — correctness proven (r6/r7/r8).
// ---------------------------------------------------------------------------
template <typename OutT>
__device__ __forceinline__ void gemm_body(
    const u16* __restrict__ A, const u16* __restrict__ W,
    const u16* __restrict__ bias, OutT* __restrict__ C,
    int M, int N, int K)
{
    __shared__ __align__(16) u16 As[128 * 32];
    __shared__ __align__(16) u16 Bs[128 * 32];

    const int t    = threadIdx.x;
    const int wave = t >> 6;
    const int ln   = t & 15;
    const int qd   = (t >> 4) & 3;
    const int m0   = blockIdx.x * 128;
    const int n0   = blockIdx.y * 128;
    const int wm   = (wave >> 1) * 64;
    const int wn   = (wave & 1) * 64;

    const int srow = t >> 2;
    const int scol = (t & 3) * 8;
    const u16* gA = A + (size_t)(m0 + srow) * K + scol;
    const u16* gB = W + (size_t)(n0 + srow) * K + scol;
    u16* lA = &As[wave * 512];
    u16* lB = &Bs[wave * 512];

    f32x4 acc[4][4] = {};

    for (int k0 = 0; k0 < K; k0 += 32) {
        __syncthreads();
        gload_lds16(gA + k0,                   lA);
        gload_lds16(gA + (size_t)64 * K + k0,  lA + 2048);
        gload_lds16(gB + k0,                   lB);
        gload_lds16(gB + (size_t)64 * K + k0,  lB + 2048);
        __syncthreads();

        bf16x8 af[4], bfr[4];
#pragma unroll
        for (int i = 0; i < 4; ++i)
            af[i] = *(const bf16x8*)&As[(wm + i * 16 + ln) * 32 + qd * 8];
#pragma unroll
        for (int j = 0; j < 4; ++j)
            bfr[j] = *(const bf16x8*)&Bs[(wn + j * 16 + ln) * 32 + qd * 8];
#pragma unroll
        for (int i = 0; i < 4; ++i)
#pragma unroll
            for (int j = 0; j < 4; ++j)
                acc[i][j] = __builtin_amdgcn_mfma_f32_16x16x32_bf16(
                    af[i], bfr[j], acc[i][j], 0, 0, 0);
    }

    float bv[4];
#pragma unroll
    for (int j = 0; j < 4; ++j) bv[j] = bf2f(bias[n0 + wn + j * 16 + ln]);

#pragma unroll
    for (int i = 0; i < 4; ++i)
#pragma unroll
        for (int r = 0; r < 4; ++r) {
            int row = m0 + wm + i * 16 + qd * 4 + r;
            OutT* crow = C + (size_t)row * N + n0 + wn + ln;
#pragma unroll
            for (int j = 0; j < 4; ++j) {
                float v = acc[i][j][r] + bv[j];
                if constexpr (sizeof(OutT) == 2) crow[j * 16] = f2bf(v);
                else                             crow[j * 16] = v;
            }
        }
}

__global__ __launch_bounds__(256) void gemm_qkv(
    const u16* __restrict__ A,
    const u16* __restrict__ W0, const u16* __restrict__ W1, const u16* __restrict__ W2,
    const u16* __restrict__ b0, const u16* __restrict__ b1, const u16* __restrict__ b2,
    u16* __restrict__ C0, u16* __restrict__ C1, u16* __restrict__ C2,
    int M, int N, int K)
{
    const u16* W; const u16* bias; u16* C;
    if (blockIdx.z == 0)      { W = W0; bias = b0; C = C0; }
    else if (blockIdx.z == 1) { W = W1; bias = b1; C = C1; }
    else                      { W = W2; bias = b2; C = C2; }
    gemm_body<u16>(A, W, bias, C, M, N, K);
}

__global__ __launch_bounds__(256) void gemm_final_f32(
    const u16* __restrict__ A, const u16* __restrict__ W,
    const u16* __restrict__ bias, float* __restrict__ C, int M, int N, int K)
{
    gemm_body<float>(A, W, bias, C, M, N, K);
}

// ---------------------------------------------------------------------------
// V transpose: V[b*S+s][h*64+d]  ->  VT[(bh*64+d)][s]   (per-head d-major).
// 64x64 tiles through LDS; ~32 MB total traffic (~6 us). Proven correct (r12).
// ---------------------------------------------------------------------------
__global__ __launch_bounds__(256) void transpose_v(
    const u16* __restrict__ V, u16* __restrict__ VT)
{
    __shared__ u16 T[64][72];           // +8 pad: 144 B row stride (16B-aligned)
    const int st = blockIdx.x;          // s-tile (0..31)
    const int bh = blockIdx.y;          // 0..63
    const int b  = bh >> 4;
    const int h  = bh & 15;
    const int t  = threadIdx.x;

    const int sr = t >> 2;              // local s row 0..63
    const int dc = (t & 3) * 16;        // d chunk 0,16,32,48
    const u16* src = V + ((size_t)b * SEQ + st * 64 + sr) * D_MODEL + h * 64 + dc;
    const uint4 a0 = *(const uint4*)src;
    const uint4 a1 = *(const uint4*)(src + 8);
#pragma unroll
    for (int e = 0; e < 8; ++e) T[dc + e][sr]     = u4get(a0, e);
#pragma unroll
    for (int e = 0; e < 8; ++e) T[dc + 8 + e][sr] = u4get(a1, e);
    __syncthreads();

    const int d  = t >> 2;              // 0..63
    const int sc = (t & 3) * 16;        // 0,16,32,48
    u16* dst = VT + ((size_t)bh * 64 + d) * SEQ + st * 64 + sc;
    *(uint4*)dst       = *(const uint4*)&T[d][sc];
    *(uint4*)(dst + 8) = *(const uint4*)&T[d][sc + 8];
}

// ---------------------------------------------------------------------------
// Flash attention, causal — round 16 (= r15 with EXP2_FAST compile fix):
//   * PAIRING: block x=p (0..31) processes q-tiles {p, 63-p} sequentially:
//     total length 33 kt-iters for EVERY p -> uniform resident blocks,
//     fixes the intra-CU tail (r14: occupancy 14%, ~1.1 waves/SIMD).
//   * exp2-domain softmax: fold 0.125*log2(e) into one scale; EXP2_FAST
//     lowers to bare v_exp_f32.
//   * defer-max (T13, THR=8 in log2 domain): skip alpha/rescale pass when
//     __all(mx <= m+8); P bounded by 2^8, fp32 l has headroom.
//   * s_setprio(1) around both MFMA clusters (m191).
// Grid: x = 32 (pairs), y = 64 (b*h); 1 wave/block; LDS 12 KB.
// ---------------------------------------------------------------------------
__global__ __launch_bounds__(64) void flash_attn(
    const u16* __restrict__ Qg, const u16* __restrict__ Kg,
    const u16* __restrict__ VTg, u16* __restrict__ Og)
{
    __shared__ __align__(16) u16 Vsh[64 * 64];   // VT tile, swizzled
    __shared__ __align__(16) u16 Psh[32 * 64];

    const int lane = threadIdx.x;       // 0..63
    const int ln   = lane & 15;
    const int qd   = lane >> 4;
    const int psw  = (ln & 7) << 3;     // P swizzle (u16 elems)

    const int pr = blockIdx.x;          // pair index 0..31
    const int bh = blockIdx.y;
    const int b  = bh >> 4;
    const int h  = bh & 15;
    const int h0 = h * 64;
    const size_t rowBase = (size_t)b * SEQ * D_MODEL;

    // VT staging source coords (dest is linear lane*16B per call)
    const int vdG = lane >> 3;          // 0..7 (= d&7 for every call)
    const int vsw = ((lane & 7) * 8) ^ (vdG << 3);
    const u16* vtRow0 = VTg + ((size_t)(bh * 64 + vdG)) * SEQ + vsw;

    const float SCL = 0.18033688011112042f;   // 0.125 * log2(e)

#pragma unroll 1
    for (int sel = 0; sel < 2; ++sel) {
        const int qw  = sel ? (63 - pr) : pr;
        const int qw0 = qw * 32;
        const int ktMax = qw >> 1;      // last K-tile (only one needing mask)

        // ---- Q fragments straight from global: B-frag [n=q=ln][k=qd*8+e] ----
        bf16x8 qf[2][2];
#pragma unroll
        for (int i = 0; i < 2; ++i)
#pragma unroll
            for (int ks = 0; ks < 2; ++ks)
                qf[i][ks] = *(const bf16x8*)(Qg + rowBase
                    + (size_t)(qw0 + i * 16 + ln) * D_MODEL + h0 + ks * 32 + qd * 8);

        float m_run[2], l_run[2];
#pragma unroll
        for (int i = 0; i < 2; ++i) { m_run[i] = -30000.0f; l_run[i] = 0.f; }
        f32x4 oacc[2][4] = {};

        for (int kt = 0; kt <= ktMax; ++kt) {
            __syncthreads();             // prev iter's Vsh/Psh reads done
            // ---- stage VT tile (64d x 64s) async; source pre-swizzled ----
            {
                const u16* vbase = vtRow0 + kt * 64;
#pragma unroll
                for (int p = 0; p < 8; ++p)
                    gload_lds16(vbase + (size_t)(p * 8) * SEQ, &Vsh[p * 512]);
            }

            // ---- S^T = K Q^T (K fragments straight from global) ----
            f32x4 sacc[4][2] = {};
#pragma unroll
            for (int ks = 0; ks < 2; ++ks) {
                bf16x8 kf[4];
#pragma unroll
                for (int j = 0; j < 4; ++j)
                    kf[j] = *(const bf16x8*)(Kg + rowBase
                        + (size_t)(kt * 64 + j * 16 + ln) * D_MODEL + h0 + ks * 32 + qd * 8);
                __builtin_amdgcn_s_setprio(1);
#pragma unroll
                for (int j = 0; j < 4; ++j)
#pragma unroll
                    for (int i = 0; i < 2; ++i)
                        sacc[j][i] = __builtin_amdgcn_mfma_f32_16x16x32_bf16(
                            kf[j], qf[i][ks], sacc[j][i], 0, 0, 0);
                __builtin_amdgcn_s_setprio(0);
            }

            // ---- scale to log2 domain (+ mask on the diagonal tile) ----
            if (kt == ktMax) {
#pragma unroll
                for (int j = 0; j < 4; ++j)
#pragma unroll
                    for (int r = 0; r < 4; ++r) {
                        const int kpos = kt * 64 + j * 16 + qd * 4 + r;
#pragma unroll
                        for (int i = 0; i < 2; ++i) {
                            const int qpos = qw0 + i * 16 + ln;
                            float s = sacc[j][i][r] * SCL;
                            sacc[j][i][r] = (kpos > qpos) ? -30000.0f : s;
                        }
                    }
            } else {
#pragma unroll
                for (int j = 0; j < 4; ++j)
#pragma unroll
                    for (int i = 0; i < 2; ++i)
#pragma unroll
                        for (int r = 0; r < 4; ++r)
                            sacc[j][i][r] *= SCL;
            }

            // ---- online softmax (log2 domain, lane-local) ----
            float mx[2];
#pragma unroll
            for (int i = 0; i < 2; ++i) {
                float m0 = sacc[0][i][0];
#pragma unroll
                for (int j = 0; j < 4; ++j)
#pragma unroll
                    for (int r = 0; r < 4; ++r) m0 = fmaxf(m0, sacc[j][i][r]);
                m0 = fmaxf(m0, __shfl_xor(m0, 16));
                m0 = fmaxf(m0, __shfl_xor(m0, 32));
                mx[i] = m0;
            }

            // defer-max: skip rescale when max growth <= 8 (p <= 2^8)
            const bool grow = !(__all((mx[0] <= m_run[0] + 8.f) &&
                                      (mx[1] <= m_run[1] + 8.f)));
            if (grow) {
#pragma unroll
                for (int i = 0; i < 2; ++i) {
                    const float mo = m_run[i];
                    const float mn = fmaxf(mo, mx[i]);
                    const float alpha = EXP2_FAST(mo - mn);
                    m_run[i] = mn;
                    l_run[i] *= alpha;
#pragma unroll
                    for (int r = 0; r < 4; ++r) {
                        const float ar = __shfl(alpha, qd * 4 + r);
#pragma unroll
                        for (int j = 0; j < 4; ++j) oacc[i][j][r] *= ar;
                    }
                }
            }

#pragma unroll
            for (int i = 0; i < 2; ++i) {
                const float mn = m_run[i];
                float rs = 0.f;
#pragma unroll
                for (int j = 0; j < 4; ++j) {
                    u16 tp[4];
#pragma unroll
                    for (int r = 0; r < 4; ++r) {
                        float p = EXP2_FAST(sacc[j][i][r] - mn);
                        rs += p;
                        tp[r] = f2bf_trunc(p);
                    }
                    uint2 w;
                    w.x = (uint32_t)tp[0] | ((uint32_t)tp[1] << 16);
                    w.y = (uint32_t)tp[2] | ((uint32_t)tp[3] << 16);
                    *(uint2*)&Psh[(i * 16 + ln) * 64 + ((j * 16 + qd * 4) ^ psw)] = w;
                }
                rs += __shfl_xor(rs, 16);
                rs += __shfl_xor(rs, 32);
                l_run[i] += rs;
            }

            __syncthreads();             // VT staged (vmcnt) + P visible

            // ---- O += P V : all-vector LDS reads ----
#pragma unroll
            for (int ks = 0; ks < 2; ++ks) {
                bf16x8 pa[2];            // A-frags of P: row = q = i*16+ln
#pragma unroll
                for (int i = 0; i < 2; ++i)
                    pa[i] = *(const bf16x8*)&Psh[(i * 16 + ln) * 64
                                                 + ((ks * 32 + qd * 8) ^ psw)];
                __builtin_amdgcn_s_setprio(1);
#pragma unroll
                for (int j = 0; j < 4; ++j) {
                    const int d = j * 16 + ln;
                    const bf16x8 vb = *(const bf16x8*)&Vsh[d * 64
                        + ((ks * 32 + qd * 8) ^ ((ln & 7) << 3))];
#pragma unroll
                    for (int i = 0; i < 2; ++i)
                        oacc[i][j] = __builtin_amdgcn_mfma_f32_16x16x32_bf16(
                            pa[i], vb, oacc[i][j], 0, 0, 0);
                }
                __builtin_amdgcn_s_setprio(0);
            }
        }

        // ---- epilogue: O / l  (l lives at lane ln'=qd*4+r, shuffle in) ----
#pragma unroll
        for (int i = 0; i < 2; ++i)
#pragma unroll
            for (int r = 0; r < 4; ++r) {
                const float lr = __shfl(l_run[i], qd * 4 + r);
                const float inv = 1.f / lr;
                const int qrow = qw0 + i * 16 + qd * 4 + r;
                u16* orow = Og + rowBase + (size_t)qrow * D_MODEL + h0 + ln;
#pragma unroll
                for (int j = 0; j < 4; ++j)
                    orow[j * 16] = f2bf(oacc[i][j][r] * inv);
            }
    }
}

// ---------------------------------------------------------------------------
static inline bool ranges_overlap(const void* a, size_t an, const void* b, size_t bn) {
    uintptr_t x0 = (uintptr_t)a, x1 = x0 + an;
    uintptr_t y0 = (uintptr_t)b, y1 = y0 + bn;
    return x0 < y1 && y0 < x1;
}

extern "C" void kernel_launch(void* const* d_in, const int* in_sizes, int n_in,
                              void* d_out, int out_size, void* d_ws, size_t ws_size,
                              hipStream_t stream)
{
    int e = 0;
    const int expect[9] = { 8388608, 1048576, 1024, 1048576, 1024,
                            1048576, 1024, 1048576, 1024 };
    if (n_in != 9) e = 59;
    if (!e) for (int i = 0; i < 9; ++i)
        if (in_sizes[i] != expect[i]) { e = 60 + i; break; }
    if (!e && out_size != (int)NXE) e = 53;
    if (!e && ranges_overlap(d_ws, ws_size, d_out, (size_t)out_size * 4)) e = 55;

    const size_t NX = NXE;
    const size_t NW = (size_t)D_MODEL * D_MODEL;
    const size_t NB = D_MODEL;

    // ws need: flag(64) + 4 weights + 4 biases + K + V = 40.0 MB (proven safe r7/r8).
    const size_t need = (64 + 4 * NW + 4 * NB + 2 * NX) * 2;
    if (!e && ws_size < need) e = 50;
    if (e) { diag_write<<<2048, 256, 0, stream>>>((float*)d_out, ldexpf(1.0f, e)); return; }

    // ws layout (u16 elems): flag | Wq Wk Wv Wo | bq bk bv bo | K | V
    u16* ws   = (u16*)d_ws;
    int* flag = (int*)ws;
    u16* Wqb  = ws + 64;
    u16* Wkb  = Wqb + NW;
    u16* Wvb  = Wkb + NW;
    u16* Wob  = Wvb + NW;
    u16* bqb  = Wob + NW;
    u16* bkb  = bqb + NB;
    u16* bvb  = bkb + NB;
    u16* bob  = bvb + NB;
    u16* Kw   = bob + NB;
    u16* Vw   = Kw  + NX;

    // Region lifetimes:
    //   d_out lower 16MB: xb (dead after gemm_qkv) -> VT (dead after flash)
    //   d_out upper 16MB: Qw (dead after flash)
    //   ws Vw: V (dead after transpose_v) -> Ow (attention output)
    //   gemm_final reads Ow (ws), writes fp32 DIRECTLY to d_out (no memcpy).
    u16* xb  = (u16*)d_out;          // x_bf16; dead after QKV gemm
    u16* Qw  = xb + NX;              // Q plane (upper half)
    u16* VTw = xb;                   // V^T reuses lower half
    u16* Ow  = Vw;                   // attention out over dead V plane

    detect_dtype<<<1, 256, 0, stream>>>((const u16*)d_in[0], flag);

    CvtArgs ca;
    const void* srcs[9] = { d_in[0], d_in[1], d_in[3], d_in[5], d_in[7],
                            d_in[2], d_in[4], d_in[6], d_in[8] };
    u16* dsts[9] = { xb, Wqb, Wkb, Wvb, Wob, bqb, bkb, bvb, bob };
    int  ns[9]   = { (int)NX, (int)NW, (int)NW, (int)NW, (int)NW,
                     (int)NB, (int)NB, (int)NB, (int)NB };
    for (int i = 0; i < 9; ++i) { ca.src[i] = srcs[i]; ca.dst[i] = dsts[i]; ca.n[i] = ns[i]; }
    cvt_all<<<dim3((unsigned)((NX + 2047) / 2048), 9), 256, 0, stream>>>(ca, flag);

    gemm_qkv<<<dim3(MTOT / 128, D_MODEL / 128, 3), 256, 0, stream>>>(
        xb, Wqb, Wkb, Wvb, bqb, bkb, bvb, Qw, Kw, Vw, MTOT, D_MODEL, D_MODEL);

    transpose_v<<<dim3(SEQ / 64, BATCH * NHEAD), 256, 0, stream>>>(Vw, VTw);

    flash_attn<<<dim3(SEQ / 64, BATCH * NHEAD), 64, 0, stream>>>(Qw, Kw, VTw, Ow);

    gemm_final_f32<<<dim3(MTOT / 128, D_MODEL / 128), 256, 0, stream>>>(
        Ow, Wob, bob, (float*)d_out, MTOT, D_MODEL, D_MODEL);
}

// Round 8
// 356.645 us; speedup vs baseline: 1.0522x; 1.0522x over previous
//
#include <hip/hip_runtime.h>
#include <cstdint>
#include <cmath>

typedef unsigned short u16;
typedef __attribute__((ext_vector_type(4))) float f32x4;
typedef __attribute__((ext_vector_type(8))) short bf16x8;

#define D_MODEL 1024
#define SEQ     2048
#define BATCH   4
#define NHEAD   16
#define MTOT    (BATCH*SEQ)      /* 8192 rows */
#define NXE     ((size_t)MTOT * D_MODEL)   /* 8,388,608 elems per plane */

static_assert(sizeof(bf16x8) == 16, "frag size");

__device__ __forceinline__ float bf2f(u16 u) {
    union { uint32_t i; float f; } v; v.i = ((uint32_t)u) << 16; return v.f;
}
__device__ __forceinline__ u16 f2bf(float x) {
    union { float f; uint32_t i; } v; v.f = x;
    uint32_t r = (v.i + 0x7FFFu + ((v.i >> 16) & 1u)) >> 16;   // RNE
    return (u16)r;
}
__device__ __forceinline__ u16 f2bf_trunc(float x) {          // cheap: P only
    union { float f; uint32_t i; } v; v.f = x;
    return (u16)(v.i >> 16);
}

// exp2 that lowers to a bare v_exp_f32 (HIP has no __exp2f; glibc macro clash)
#if defined(__has_builtin)
#if __has_builtin(__builtin_amdgcn_exp2f)
#define EXP2_FAST(x) __builtin_amdgcn_exp2f(x)
#endif
#endif
#ifndef EXP2_FAST
#define EXP2_FAST(x) exp2f(x)
#endif

typedef const __attribute__((address_space(1))) void* gptr_t;
typedef __attribute__((address_space(3))) void* sptr_t;
__device__ __forceinline__ void gload_lds16(const void* g, void* l) {
    __builtin_amdgcn_global_load_lds((gptr_t)g, (sptr_t)l, 16, 0, 0);
}

// extract u16 element e (compile-time const after unroll) from a uint4
__device__ __forceinline__ u16 u4get(const uint4& v, int e) {
    const uint32_t w = ((e >> 1) == 0) ? v.x : ((e >> 1) == 1) ? v.y
                     : ((e >> 1) == 2) ? v.z : v.w;
    return (u16)((e & 1) ? (w >> 16) : (w & 0xFFFFu));
}

// ---------------------------------------------------------------------------
// Precondition-failure flood: d_out is fp32; absmax report encodes 2^e.
// ---------------------------------------------------------------------------
__global__ __launch_bounds__(256) void diag_write(float* __restrict__ out, float v) {
    size_t i = (size_t)blockIdx.x * 256 + threadIdx.x;
    for (; i < NXE; i += (size_t)gridDim.x * 256) out[i] = v;
}

// ---------------------------------------------------------------------------
// Dtype sniffer (validated r3/r5/r6: inputs are fp32 -> flag=0).
// ---------------------------------------------------------------------------
__global__ void detect_dtype(const u16* __restrict__ x, int* __restrict__ flag) {
    __shared__ int cnt;
    if (threadIdx.x == 0) cnt = 0;
    __syncthreads();
    int c = 0;
#pragma unroll
    for (int k = 0; k < 16; ++k) {
        u16 e = x[2 * (threadIdx.x * 16 + k)];
        int ex = (e >> 7) & 0xFF;
        if (e == 0 || (ex >= 100 && ex <= 140)) ++c;
    }
    atomicAdd(&cnt, c);
    __syncthreads();
    if (threadIdx.x == 0) *flag = (cnt >= 3500) ? 1 : 0;
}

// ---------------------------------------------------------------------------
// Normalize inputs to bf16 planes (fp32 -> RNE downconvert; bf16 -> copy).
// ---------------------------------------------------------------------------
struct CvtArgs { const void* src[9]; u16* dst[9]; int n[9]; };

__global__ __launch_bounds__(256) void cvt_all(CvtArgs a, const int* __restrict__ flag) {
    const int seg = blockIdx.y;
    const int n = a.n[seg];
    const int i = (blockIdx.x * 256 + threadIdx.x) * 8;
    if (i >= n) return;
    u16* d = a.dst[seg] + i;
    if (*flag) {
        *(uint4*)d = *(const uint4*)((const u16*)a.src[seg] + i);
    } else {
        const float* s = (const float*)a.src[seg] + i;
        u16 tmp[8];
#pragma unroll
        for (int k = 0; k < 8; ++k) tmp[k] = f2bf(s[k]);
        *(uint4*)d = *(uint4*)tmp;
    }
}

// ---------------------------------------------------------------------------
// MFMA GEMM (m97 structure, 128x128, BK=32) — correctness proven (r6/r7/r8).
// ---------------------------------------------------------------------------
template <typename OutT>
__device__ __forceinline__ void gemm_body(
    const u16* __restrict__ A, const u16* __restrict__ W,
    const u16* __restrict__ bias, OutT* __restrict__ C,
    int M, int N, int K)
{
    __shared__ __align__(16) u16 As[128 * 32];
    __shared__ __align__(16) u16 Bs[128 * 32];

    const int t    = threadIdx.x;
    const int wave = t >> 6;
    const int ln   = t & 15;
    const int qd   = (t >> 4) & 3;
    const int m0   = blockIdx.x * 128;
    const int n0   = blockIdx.y * 128;
    const int wm   = (wave >> 1) * 64;
    const int wn   = (wave & 1) * 64;

    const int srow = t >> 2;
    const int scol = (t & 3) * 8;
    const u16* gA = A + (size_t)(m0 + srow) * K + scol;
    const u16* gB = W + (size_t)(n0 + srow) * K + scol;
    u16* lA = &As[wave * 512];
    u16* lB = &Bs[wave * 512];

    f32x4 acc[4][4] = {};

    for (int k0 = 0; k0 < K; k0 += 32) {
        __syncthreads();
        gload_lds16(gA + k0,                   lA);
        gload_lds16(gA + (size_t)64 * K + k0,  lA + 2048);
        gload_lds16(gB + k0,                   lB);
        gload_lds16(gB + (size_t)64 * K + k0,  lB + 2048);
        __syncthreads();

        bf16x8 af[4], bfr[4];
#pragma unroll
        for (int i = 0; i < 4; ++i)
            af[i] = *(const bf16x8*)&As[(wm + i * 16 + ln) * 32 + qd * 8];
#pragma unroll
        for (int j = 0; j < 4; ++j)
            bfr[j] = *(const bf16x8*)&Bs[(wn + j * 16 + ln) * 32 + qd * 8];
#pragma unroll
        for (int i = 0; i < 4; ++i)
#pragma unroll
            for (int j = 0; j < 4; ++j)
                acc[i][j] = __builtin_amdgcn_mfma_f32_16x16x32_bf16(
                    af[i], bfr[j], acc[i][j], 0, 0, 0);
    }

    float bv[4];
#pragma unroll
    for (int j = 0; j < 4; ++j) bv[j] = bf2f(bias[n0 + wn + j * 16 + ln]);

#pragma unroll
    for (int i = 0; i < 4; ++i)
#pragma unroll
        for (int r = 0; r < 4; ++r) {
            int row = m0 + wm + i * 16 + qd * 4 + r;
            OutT* crow = C + (size_t)row * N + n0 + wn + ln;
#pragma unroll
            for (int j = 0; j < 4; ++j) {
                float v = acc[i][j][r] + bv[j];
                if constexpr (sizeof(OutT) == 2) crow[j * 16] = f2bf(v);
                else                             crow[j * 16] = v;
            }
        }
}

__global__ __launch_bounds__(256) void gemm_qkv(
    const u16* __restrict__ A,
    const u16* __restrict__ W0, const u16* __restrict__ W1, const u16* __restrict__ W2,
    const u16* __restrict__ b0, const u16* __restrict__ b1, const u16* __restrict__ b2,
    u16* __restrict__ C0, u16* __restrict__ C1, u16* __restrict__ C2,
    int M, int N, int K)
{
    const u16* W; const u16* bias; u16* C;
    if (blockIdx.z == 0)      { W = W0; bias = b0; C = C0; }
    else if (blockIdx.z == 1) { W = W1; bias = b1; C = C1; }
    else                      { W = W2; bias = b2; C = C2; }
    gemm_body<u16>(A, W, bias, C, M, N, K);
}

__global__ __launch_bounds__(256) void gemm_final_f32(
    const u16* __restrict__ A, const u16* __restrict__ W,
    const u16* __restrict__ bias, float* __restrict__ C, int M, int N, int K)
{
    gemm_body<float>(A, W, bias, C, M, N, K);
}

// ---------------------------------------------------------------------------
// V transpose: V[b*S+s][h*64+d]  ->  VT[(bh*64+d)][s]   (per-head d-major).
// 64x64 tiles through LDS; ~32 MB total traffic (~6 us). Proven correct (r12).
// ---------------------------------------------------------------------------
__global__ __launch_bounds__(256) void transpose_v(
    const u16* __restrict__ V, u16* __restrict__ VT)
{
    __shared__ u16 T[64][72];           // +8 pad: 144 B row stride (16B-aligned)
    const int st = blockIdx.x;          // s-tile (0..31)
    const int bh = blockIdx.y;          // 0..63
    const int b  = bh >> 4;
    const int h  = bh & 15;
    const int t  = threadIdx.x;

    const int sr = t >> 2;              // local s row 0..63
    const int dc = (t & 3) * 16;        // d chunk 0,16,32,48
    const u16* src = V + ((size_t)b * SEQ + st * 64 + sr) * D_MODEL + h * 64 + dc;
    const uint4 a0 = *(const uint4*)src;
    const uint4 a1 = *(const uint4*)(src + 8);
#pragma unroll
    for (int e = 0; e < 8; ++e) T[dc + e][sr]     = u4get(a0, e);
#pragma unroll
    for (int e = 0; e < 8; ++e) T[dc + 8 + e][sr] = u4get(a1, e);
    __syncthreads();

    const int d  = t >> 2;              // 0..63
    const int sc = (t & 3) * 16;        // 0,16,32,48
    u16* dst = VT + ((size_t)bh * 64 + d) * SEQ + st * 64 + sc;
    *(uint4*)dst       = *(const uint4*)&T[d][sc];
    *(uint4*)(dst + 8) = *(const uint4*)&T[d][sc + 8];
}

// ---------------------------------------------------------------------------
// Flash attention, causal — round 17: MERGED-SWEEP PAIRING.
//   Block (pr, bh) owns q-tiles A=pr and B=63-pr, ONE kt loop 0..ktMaxB:
//     - tile A active while kt <= ktMaxA (heavy iters), B always.
//     - heavy iters share kf (QK^T) and vb (PV) fragments for both tiles.
//   Why: R7's sequential phases de-synchronized same-plane kt sweeps ->
//   L2 thrash (FETCH 134->466 MB). Merged sweep keeps all blocks of a
//   plane starting kt=0 together, monotone (r14's low-fetch property),
//   AND keeps uniform per-block work: 2*(ktMaxA+1) + (ktMaxB-ktMaxA)
//   = 33 MFMA-units for every pr -> no intra-CU tail.
//   Retained: exp2-domain softmax, defer-max THR=8, s_setprio, swizzled
//   VT staging via global_load_lds, lane-local softmax (swapped QK^T).
// Grid: x = 32 (pairs), y = 64 (b*h); 1 wave/block; LDS 16 KB.
// ---------------------------------------------------------------------------
__global__ __launch_bounds__(64) void flash_attn(
    const u16* __restrict__ Qg, const u16* __restrict__ Kg,
    const u16* __restrict__ VTg, u16* __restrict__ Og)
{
    __shared__ __align__(16) u16 Vsh[64 * 64];    // VT tile, swizzled
    __shared__ __align__(16) u16 PshA[32 * 64];
    __shared__ __align__(16) u16 PshB[32 * 64];

    const int lane = threadIdx.x;       // 0..63
    const int ln   = lane & 15;
    const int qd   = lane >> 4;
    const int psw  = (ln & 7) << 3;     // P swizzle (u16 elems)

    const int pr = blockIdx.x;          // pair index 0..31
    const int bh = blockIdx.y;
    const int b  = bh >> 4;
    const int h  = bh & 15;
    const int h0 = h * 64;
    const size_t rowBase = (size_t)b * SEQ * D_MODEL;

    const int qwA = pr,       qw0A = qwA * 32, ktMaxA = qwA >> 1;
    const int qwB = 63 - pr,  qw0B = qwB * 32, ktMaxB = qwB >> 1;

    // VT staging source coords (dest is linear lane*16B per call)
    const int vdG = lane >> 3;          // 0..7 (= d&7 for every call)
    const int vsw = ((lane & 7) * 8) ^ (vdG << 3);
    const u16* vtRow0 = VTg + ((size_t)(bh * 64 + vdG)) * SEQ + vsw;

    const float SCL = 0.18033688011112042f;   // 0.125 * log2(e)

    // ---- Q fragments (B-frag [n=q=ln][k=qd*8+e]) for both tiles ----
    bf16x8 qfA[2][2], qfB[2][2];
#pragma unroll
    for (int i = 0; i < 2; ++i)
#pragma unroll
        for (int ks = 0; ks < 2; ++ks) {
            qfA[i][ks] = *(const bf16x8*)(Qg + rowBase
                + (size_t)(qw0A + i * 16 + ln) * D_MODEL + h0 + ks * 32 + qd * 8);
            qfB[i][ks] = *(const bf16x8*)(Qg + rowBase
                + (size_t)(qw0B + i * 16 + ln) * D_MODEL + h0 + ks * 32 + qd * 8);
        }

    float mA[2], lA[2], mB[2], lB[2];
#pragma unroll
    for (int i = 0; i < 2; ++i) {
        mA[i] = -30000.0f; lA[i] = 0.f;
        mB[i] = -30000.0f; lB[i] = 0.f;
    }
    f32x4 oA[2][4] = {}, oB[2][4] = {};

    // scale+mask helper is inlined twice below; softmax as lambda (compile-
    // time inlined, all indices constant after unroll).
    auto softmax_tile = [&](f32x4 (&sacc)[4][2], float (&m_run)[2],
                            float (&l_run)[2], f32x4 (&oacc)[2][4], u16* P) {
        float mx[2];
#pragma unroll
        for (int i = 0; i < 2; ++i) {
            float m0 = sacc[0][i][0];
#pragma unroll
            for (int j = 0; j < 4; ++j)
#pragma unroll
                for (int r = 0; r < 4; ++r) m0 = fmaxf(m0, sacc[j][i][r]);
            m0 = fmaxf(m0, __shfl_xor(m0, 16));
            m0 = fmaxf(m0, __shfl_xor(m0, 32));
            mx[i] = m0;
        }
        const bool grow = !(__all((mx[0] <= m_run[0] + 8.f) &&
                                  (mx[1] <= m_run[1] + 8.f)));
        if (grow) {
#pragma unroll
            for (int i = 0; i < 2; ++i) {
                const float mo = m_run[i];
                const float mn = fmaxf(mo, mx[i]);
                const float alpha = EXP2_FAST(mo - mn);
                m_run[i] = mn;
                l_run[i] *= alpha;
#pragma unroll
                for (int r = 0; r < 4; ++r) {
                    const float ar = __shfl(alpha, qd * 4 + r);
#pragma unroll
                    for (int j = 0; j < 4; ++j) oacc[i][j][r] *= ar;
                }
            }
        }
#pragma unroll
        for (int i = 0; i < 2; ++i) {
            const float mn = m_run[i];
            float rs = 0.f;
#pragma unroll
            for (int j = 0; j < 4; ++j) {
                u16 tp[4];
#pragma unroll
                for (int r = 0; r < 4; ++r) {
                    float p = EXP2_FAST(sacc[j][i][r] - mn);
                    rs += p;
                    tp[r] = f2bf_trunc(p);
                }
                uint2 w;
                w.x = (uint32_t)tp[0] | ((uint32_t)tp[1] << 16);
                w.y = (uint32_t)tp[2] | ((uint32_t)tp[3] << 16);
                *(uint2*)&P[(i * 16 + ln) * 64 + ((j * 16 + qd * 4) ^ psw)] = w;
            }
            rs += __shfl_xor(rs, 16);
            rs += __shfl_xor(rs, 32);
            l_run[i] += rs;
        }
    };

    for (int kt = 0; kt <= ktMaxB; ++kt) {
        const bool heavy = (kt <= ktMaxA);   // wave-uniform

        __syncthreads();                 // prev iter's Vsh reads done
        // ---- stage VT tile (64d x 64s) async; source pre-swizzled ----
        {
            const u16* vbase = vtRow0 + kt * 64;
#pragma unroll
            for (int p = 0; p < 8; ++p)
                gload_lds16(vbase + (size_t)(p * 8) * SEQ, &Vsh[p * 512]);
        }

        // ---- S^T = K Q^T, shared kf for both tiles ----
        f32x4 sA[4][2] = {}, sB[4][2] = {};
#pragma unroll
        for (int ks = 0; ks < 2; ++ks) {
            bf16x8 kf[4];
#pragma unroll
            for (int j = 0; j < 4; ++j)
                kf[j] = *(const bf16x8*)(Kg + rowBase
                    + (size_t)(kt * 64 + j * 16 + ln) * D_MODEL + h0 + ks * 32 + qd * 8);
            __builtin_amdgcn_s_setprio(1);
            if (heavy) {
#pragma unroll
                for (int j = 0; j < 4; ++j)
#pragma unroll
                    for (int i = 0; i < 2; ++i)
                        sA[j][i] = __builtin_amdgcn_mfma_f32_16x16x32_bf16(
                            kf[j], qfA[i][ks], sA[j][i], 0, 0, 0);
            }
#pragma unroll
            for (int j = 0; j < 4; ++j)
#pragma unroll
                for (int i = 0; i < 2; ++i)
                    sB[j][i] = __builtin_amdgcn_mfma_f32_16x16x32_bf16(
                        kf[j], qfB[i][ks], sB[j][i], 0, 0, 0);
            __builtin_amdgcn_s_setprio(0);
        }

        // ---- scale to log2 domain (+ diagonal masks) ----
        if (heavy) {
            if (kt == ktMaxA) {
#pragma unroll
                for (int j = 0; j < 4; ++j)
#pragma unroll
                    for (int r = 0; r < 4; ++r) {
                        const int kpos = kt * 64 + j * 16 + qd * 4 + r;
#pragma unroll
                        for (int i = 0; i < 2; ++i) {
                            const int qpos = qw0A + i * 16 + ln;
                            float s = sA[j][i][r] * SCL;
                            sA[j][i][r] = (kpos > qpos) ? -30000.0f : s;
                        }
                    }
            } else {
#pragma unroll
                for (int j = 0; j < 4; ++j)
#pragma unroll
                    for (int i = 0; i < 2; ++i)
#pragma unroll
                        for (int r = 0; r < 4; ++r)
                            sA[j][i][r] *= SCL;
            }
        }
        if (kt == ktMaxB) {
#pragma unroll
            for (int j = 0; j < 4; ++j)
#pragma unroll
                for (int r = 0; r < 4; ++r) {
                    const int kpos = kt * 64 + j * 16 + qd * 4 + r;
#pragma unroll
                    for (int i = 0; i < 2; ++i) {
                        const int qpos = qw0B + i * 16 + ln;
                        float s = sB[j][i][r] * SCL;
                        sB[j][i][r] = (kpos > qpos) ? -30000.0f : s;
                    }
                }
        } else {
#pragma unroll
            for (int j = 0; j < 4; ++j)
#pragma unroll
                for (int i = 0; i < 2; ++i)
#pragma unroll
                    for (int r = 0; r < 4; ++r)
                        sB[j][i][r] *= SCL;
        }

        // ---- online softmax (log2 domain, lane-local) ----
        if (heavy) softmax_tile(sA, mA, lA, oA, PshA);
        softmax_tile(sB, mB, lB, oB, PshB);

        __syncthreads();                 // VT staged (vmcnt) + P visible

        // ---- O += P V : shared vb for both tiles ----
#pragma unroll
        for (int ks = 0; ks < 2; ++ks) {
            bf16x8 paA[2], paB[2];
#pragma unroll
            for (int i = 0; i < 2; ++i) {
                if (heavy)
                    paA[i] = *(const bf16x8*)&PshA[(i * 16 + ln) * 64
                                                   + ((ks * 32 + qd * 8) ^ psw)];
                paB[i] = *(const bf16x8*)&PshB[(i * 16 + ln) * 64
                                               + ((ks * 32 + qd * 8) ^ psw)];
            }
            __builtin_amdgcn_s_setprio(1);
#pragma unroll
            for (int j = 0; j < 4; ++j) {
                const int d = j * 16 + ln;
                const bf16x8 vb = *(const bf16x8*)&Vsh[d * 64
                    + ((ks * 32 + qd * 8) ^ ((ln & 7) << 3))];
                if (heavy) {
#pragma unroll
                    for (int i = 0; i < 2; ++i)
                        oA[i][j] = __builtin_amdgcn_mfma_f32_16x16x32_bf16(
                            paA[i], vb, oA[i][j], 0, 0, 0);
                }
#pragma unroll
                for (int i = 0; i < 2; ++i)
                    oB[i][j] = __builtin_amdgcn_mfma_f32_16x16x32_bf16(
                        paB[i], vb, oB[i][j], 0, 0, 0);
            }
            __builtin_amdgcn_s_setprio(0);
        }
    }

    // ---- epilogues: O / l for both tiles ----
    auto epilogue = [&](float (&l_run)[2], f32x4 (&oacc)[2][4], int qw0) {
#pragma unroll
        for (int i = 0; i < 2; ++i)
#pragma unroll
            for (int r = 0; r < 4; ++r) {
                const float lr = __shfl(l_run[i], qd * 4 + r);
                const float inv = 1.f / lr;
                const int qrow = qw0 + i * 16 + qd * 4 + r;
                u16* orow = Og + rowBase + (size_t)qrow * D_MODEL + h0 + ln;
#pragma unroll
                for (int j = 0; j < 4; ++j)
                    orow[j * 16] = f2bf(oacc[i][j][r] * inv);
            }
    };
    epilogue(lA, oA, qw0A);
    epilogue(lB, oB, qw0B);
}

// ---------------------------------------------------------------------------
static inline bool ranges_overlap(const void* a, size_t an, const void* b, size_t bn) {
    uintptr_t x0 = (uintptr_t)a, x1 = x0 + an;
    uintptr_t y0 = (uintptr_t)b, y1 = y0 + bn;
    return x0 < y1 && y0 < x1;
}

extern "C" void kernel_launch(void* const* d_in, const int* in_sizes, int n_in,
                              void* d_out, int out_size, void* d_ws, size_t ws_size,
                              hipStream_t stream)
{
    int e = 0;
    const int expect[9] = { 8388608, 1048576, 1024, 1048576, 1024,
                            1048576, 1024, 1048576, 1024 };
    if (n_in != 9) e = 59;
    if (!e) for (int i = 0; i < 9; ++i)
        if (in_sizes[i] != expect[i]) { e = 60 + i; break; }
    if (!e && out_size != (int)NXE) e = 53;
    if (!e && ranges_overlap(d_ws, ws_size, d_out, (size_t)out_size * 4)) e = 55;

    const size_t NX = NXE;
    const size_t NW = (size_t)D_MODEL * D_MODEL;
    const size_t NB = D_MODEL;

    // ws need: flag(64) + 4 weights + 4 biases + K + V = 40.0 MB (proven safe r7/r8).
    const size_t need = (64 + 4 * NW + 4 * NB + 2 * NX) * 2;
    if (!e && ws_size < need) e = 50;
    if (e) { diag_write<<<2048, 256, 0, stream>>>((float*)d_out, ldexpf(1.0f, e)); return; }

    // ws layout (u16 elems): flag | Wq Wk Wv Wo | bq bk bv bo | K | V
    u16* ws   = (u16*)d_ws;
    int* flag = (int*)ws;
    u16* Wqb  = ws + 64;
    u16* Wkb  = Wqb + NW;
    u16* Wvb  = Wkb + NW;
    u16* Wob  = Wvb + NW;
    u16* bqb  = Wob + NW;
    u16* bkb  = bqb + NB;
    u16* bvb  = bkb + NB;
    u16* bob  = bvb + NB;
    u16* Kw   = bob + NB;
    u16* Vw   = Kw  + NX;

    // Region lifetimes:
    //   d_out lower 16MB: xb (dead after gemm_qkv) -> VT (dead after flash)
    //   d_out upper 16MB: Qw (dead after flash)
    //   ws Vw: V (dead after transpose_v) -> Ow (attention output)
    //   gemm_final reads Ow (ws), writes fp32 DIRECTLY to d_out (no memcpy).
    u16* xb  = (u16*)d_out;          // x_bf16; dead after QKV gemm
    u16* Qw  = xb + NX;              // Q plane (upper half)
    u16* VTw = xb;                   // V^T reuses lower half
    u16* Ow  = Vw;                   // attention out over dead V plane

    detect_dtype<<<1, 256, 0, stream>>>((const u16*)d_in[0], flag);

    CvtArgs ca;
    const void* srcs[9] = { d_in[0], d_in[1], d_in[3], d_in[5], d_in[7],
                            d_in[2], d_in[4], d_in[6], d_in[8] };
    u16* dsts[9] = { xb, Wqb, Wkb, Wvb, Wob, bqb, bkb, bvb, bob };
    int  ns[9]   = { (int)NX, (int)NW, (int)NW, (int)NW, (int)NW,
                     (int)NB, (int)NB, (int)NB, (int)NB };
    for (int i = 0; i < 9; ++i) { ca.src[i] = srcs[i]; ca.dst[i] = dsts[i]; ca.n[i] = ns[i]; }
    cvt_all<<<dim3((unsigned)((NX + 2047) / 2048), 9), 256, 0, stream>>>(ca, flag);

    gemm_qkv<<<dim3(MTOT / 128, D_MODEL / 128, 3), 256, 0, stream>>>(
        xb, Wqb, Wkb, Wvb, bqb, bkb, bvb, Qw, Kw, Vw, MTOT, D_MODEL, D_MODEL);

    transpose_v<<<dim3(SEQ / 64, BATCH * NHEAD), 256, 0, stream>>>(Vw, VTw);

    flash_attn<<<dim3(SEQ / 64, BATCH * NHEAD), 64, 0, stream>>>(Qw, Kw, VTw, Ow);

    gemm_final_f32<<<dim3(MTOT / 128, D_MODEL / 128), 256, 0, stream>>>(
        Ow, Wob, bob, (float*)d_out, MTOT, D_MODEL, D_MODEL);
}

// Round 9
// 334.152 us; speedup vs baseline: 1.1230x; 1.0673x over previous
//
#include <hip/hip_runtime.h>
#include <cstdint>
#include <cmath>

typedef unsigned short u16;
typedef __attribute__((ext_vector_type(4))) float f32x4;
typedef __attribute__((ext_vector_type(8))) short bf16x8;

#define D_MODEL 1024
#define SEQ     2048
#define BATCH   4
#define NHEAD   16
#define MTOT    (BATCH*SEQ)      /* 8192 rows */
#define NXE     ((size_t)MTOT * D_MODEL)   /* 8,388,608 elems per plane */

static_assert(sizeof(bf16x8) == 16, "frag size");

__device__ __forceinline__ float bf2f(u16 u) {
    union { uint32_t i; float f; } v; v.i = ((uint32_t)u) << 16; return v.f;
}
__device__ __forceinline__ u16 f2bf(float x) {
    union { float f; uint32_t i; } v; v.f = x;
    uint32_t r = (v.i + 0x7FFFu + ((v.i >> 16) & 1u)) >> 16;   // RNE
    return (u16)r;
}
__device__ __forceinline__ u16 f2bf_trunc(float x) {          // cheap: P only
    union { float f; uint32_t i; } v; v.f = x;
    return (u16)(v.i >> 16);
}

// exp2 that lowers to a bare v_exp_f32 (HIP has no __exp2f; glibc macro clash)
#if defined(__has_builtin)
#if __has_builtin(__builtin_amdgcn_exp2f)
#define EXP2_FAST(x) __builtin_amdgcn_exp2f(x)
#endif
#endif
#ifndef EXP2_FAST
#define EXP2_FAST(x) exp2f(x)
#endif

typedef const __attribute__((address_space(1))) void* gptr_t;
typedef __attribute__((address_space(3))) void* sptr_t;
__device__ __forceinline__ void gload_lds16(const void* g, void* l) {
    __builtin_amdgcn_global_load_lds((gptr_t)g, (sptr_t)l, 16, 0, 0);
}

// extract u16 element e (compile-time const after unroll) from a uint4
__device__ __forceinline__ u16 u4get(const uint4& v, int e) {
    const uint32_t w = ((e >> 1) == 0) ? v.x : ((e >> 1) == 1) ? v.y
                     : ((e >> 1) == 2) ? v.z : v.w;
    return (u16)((e & 1) ? (w >> 16) : (w & 0xFFFFu));
}

// ---------------------------------------------------------------------------
// Precondition-failure flood: d_out is fp32; absmax report encodes 2^e.
// ---------------------------------------------------------------------------
__global__ __launch_bounds__(256) void diag_write(float* __restrict__ out, float v) {
    size_t i = (size_t)blockIdx.x * 256 + threadIdx.x;
    for (; i < NXE; i += (size_t)gridDim.x * 256) out[i] = v;
}

// ---------------------------------------------------------------------------
// Dtype sniffer (validated r3/r5/r6: inputs are fp32 -> flag=0).
// ---------------------------------------------------------------------------
__global__ void detect_dtype(const u16* __restrict__ x, int* __restrict__ flag) {
    __shared__ int cnt;
    if (threadIdx.x == 0) cnt = 0;
    __syncthreads();
    int c = 0;
#pragma unroll
    for (int k = 0; k < 16; ++k) {
        u16 e = x[2 * (threadIdx.x * 16 + k)];
        int ex = (e >> 7) & 0xFF;
        if (e == 0 || (ex >= 100 && ex <= 140)) ++c;
    }
    atomicAdd(&cnt, c);
    __syncthreads();
    if (threadIdx.x == 0) *flag = (cnt >= 3500) ? 1 : 0;
}

// ---------------------------------------------------------------------------
// Normalize inputs to bf16 planes (fp32 -> RNE downconvert; bf16 -> copy).
// ---------------------------------------------------------------------------
struct CvtArgs { const void* src[9]; u16* dst[9]; int n[9]; };

__global__ __launch_bounds__(256) void cvt_all(CvtArgs a, const int* __restrict__ flag) {
    const int seg = blockIdx.y;
    const int n = a.n[seg];
    const int i = (blockIdx.x * 256 + threadIdx.x) * 8;
    if (i >= n) return;
    u16* d = a.dst[seg] + i;
    if (*flag) {
        *(uint4*)d = *(const uint4*)((const u16*)a.src[seg] + i);
    } else {
        const float* s = (const float*)a.src[seg] + i;
        u16 tmp[8];
#pragma unroll
        for (int k = 0; k < 8; ++k) tmp[k] = f2bf(s[k]);
        *(uint4*)d = *(uint4*)tmp;
    }
}

// ---------------------------------------------------------------------------
// MFMA GEMM (m97 structure, 128x128, BK=32) — correctness proven (r6/r7/r8).
// ---------------------------------------------------------------------------
template <typename OutT>
__device__ __forceinline__ void gemm_body(
    const u16* __restrict__ A, const u16* __restrict__ W,
    const u16* __restrict__ bias, OutT* __restrict__ C,
    int M, int N, int K)
{
    __shared__ __align__(16) u16 As[128 * 32];
    __shared__ __align__(16) u16 Bs[128 * 32];

    const int t    = threadIdx.x;
    const int wave = t >> 6;
    const int ln   = t & 15;
    const int qd   = (t >> 4) & 3;
    const int m0   = blockIdx.x * 128;
    const int n0   = blockIdx.y * 128;
    const int wm   = (wave >> 1) * 64;
    const int wn   = (wave & 1) * 64;

    const int srow = t >> 2;
    const int scol = (t & 3) * 8;
    const u16* gA = A + (size_t)(m0 + srow) * K + scol;
    const u16* gB = W + (size_t)(n0 + srow) * K + scol;
    u16* lA = &As[wave * 512];
    u16* lB = &Bs[wave * 512];

    f32x4 acc[4][4] = {};

    for (int k0 = 0; k0 < K; k0 += 32) {
        __syncthreads();
        gload_lds16(gA + k0,                   lA);
        gload_lds16(gA + (size_t)64 * K + k0,  lA + 2048);
        gload_lds16(gB + k0,                   lB);
        gload_lds16(gB + (size_t)64 * K + k0,  lB + 2048);
        __syncthreads();

        bf16x8 af[4], bfr[4];
#pragma unroll
        for (int i = 0; i < 4; ++i)
            af[i] = *(const bf16x8*)&As[(wm + i * 16 + ln) * 32 + qd * 8];
#pragma unroll
        for (int j = 0; j < 4; ++j)
            bfr[j] = *(const bf16x8*)&Bs[(wn + j * 16 + ln) * 32 + qd * 8];
#pragma unroll
        for (int i = 0; i < 4; ++i)
#pragma unroll
            for (int j = 0; j < 4; ++j)
                acc[i][j] = __builtin_amdgcn_mfma_f32_16x16x32_bf16(
                    af[i], bfr[j], acc[i][j], 0, 0, 0);
    }

    float bv[4];
#pragma unroll
    for (int j = 0; j < 4; ++j) bv[j] = bf2f(bias[n0 + wn + j * 16 + ln]);

#pragma unroll
    for (int i = 0; i < 4; ++i)
#pragma unroll
        for (int r = 0; r < 4; ++r) {
            int row = m0 + wm + i * 16 + qd * 4 + r;
            OutT* crow = C + (size_t)row * N + n0 + wn + ln;
#pragma unroll
            for (int j = 0; j < 4; ++j) {
                float v = acc[i][j][r] + bv[j];
                if constexpr (sizeof(OutT) == 2) crow[j * 16] = f2bf(v);
                else                             crow[j * 16] = v;
            }
        }
}

__global__ __launch_bounds__(256) void gemm_qkv(
    const u16* __restrict__ A,
    const u16* __restrict__ W0, const u16* __restrict__ W1, const u16* __restrict__ W2,
    const u16* __restrict__ b0, const u16* __restrict__ b1, const u16* __restrict__ b2,
    u16* __restrict__ C0, u16* __restrict__ C1, u16* __restrict__ C2,
    int M, int N, int K)
{
    const u16* W; const u16* bias; u16* C;
    if (blockIdx.z == 0)      { W = W0; bias = b0; C = C0; }
    else if (blockIdx.z == 1) { W = W1; bias = b1; C = C1; }
    else                      { W = W2; bias = b2; C = C2; }
    gemm_body<u16>(A, W, bias, C, M, N, K);
}

__global__ __launch_bounds__(256) void gemm_final_f32(
    const u16* __restrict__ A, const u16* __restrict__ W,
    const u16* __restrict__ bias, float* __restrict__ C, int M, int N, int K)
{
    gemm_body<float>(A, W, bias, C, M, N, K);
}

// ---------------------------------------------------------------------------
// V transpose: V[b*S+s][h*64+d]  ->  VT[(bh*64+d)][s]   (per-head d-major).
// 64x64 tiles through LDS; ~32 MB total traffic (~6 us). Proven correct (r12).
// ---------------------------------------------------------------------------
__global__ __launch_bounds__(256) void transpose_v(
    const u16* __restrict__ V, u16* __restrict__ VT)
{
    __shared__ u16 T[64][72];           // +8 pad: 144 B row stride (16B-aligned)
    const int st = blockIdx.x;          // s-tile (0..31)
    const int bh = blockIdx.y;          // 0..63
    const int b  = bh >> 4;
    const int h  = bh & 15;
    const int t  = threadIdx.x;

    const int sr = t >> 2;              // local s row 0..63
    const int dc = (t & 3) * 16;        // d chunk 0,16,32,48
    const u16* src = V + ((size_t)b * SEQ + st * 64 + sr) * D_MODEL + h * 64 + dc;
    const uint4 a0 = *(const uint4*)src;
    const uint4 a1 = *(const uint4*)(src + 8);
#pragma unroll
    for (int e = 0; e < 8; ++e) T[dc + e][sr]     = u4get(a0, e);
#pragma unroll
    for (int e = 0; e < 8; ++e) T[dc + 8 + e][sr] = u4get(a1, e);
    __syncthreads();

    const int d  = t >> 2;              // 0..63
    const int sc = (t & 3) * 16;        // 0,16,32,48
    u16* dst = VT + ((size_t)bh * 64 + d) * SEQ + st * 64 + sc;
    *(uint4*)dst       = *(const uint4*)&T[d][sc];
    *(uint4*)(dst + 8) = *(const uint4*)&T[d][sc + 8];
}

// ---------------------------------------------------------------------------
// Flash attention, causal — round 18: r14 structure (135us proven: 1 wave/
// block, swapped QK^T lane-local softmax, vectorized PV via swizzled VT
// staging, grid balance) + register-neutral serial-chain cuts (numerics
// validated in r16/r17 runs; r17's regression was the PAIRING, not these):
//   * exp2-domain softmax: fold 0.125*log2(e) into SCL; EXP2_FAST = bare
//     v_exp_f32 (removes ~32 v_mul/iter vs __expf).
//   * defer-max (T13, THR=8 log2): skip alpha/rescale when no max growth.
//   * s_setprio(1) around both MFMA clusters (m191: +4-7% 1-wave attn).
// NOT kept from r17: pairing/merged-sweep (196 VGPR -> 2 waves/SIMD cliff,
// occupancy 9%; r14's 104 VGPR keeps 4 waves/SIMD capacity).
// Grid: x = 64, y = 64 (b*h); 1 wave/block; LDS 12 KB.
// ---------------------------------------------------------------------------
__global__ __launch_bounds__(64) void flash_attn(
    const u16* __restrict__ Qg, const u16* __restrict__ Kg,
    const u16* __restrict__ VTg, u16* __restrict__ Og)
{
    __shared__ __align__(16) u16 Vsh[64 * 64];   // VT tile, swizzled
    __shared__ __align__(16) u16 Psh[32 * 64];

    const int lane = threadIdx.x;       // 0..63
    const int ln   = lane & 15;
    const int qd   = lane >> 4;
    const int psw  = (ln & 7) << 3;     // P swizzle (u16 elems)

    const int bh = blockIdx.y;
    const int qw = (63 - (int)blockIdx.x + bh) & 63;   // balance fix (r11)
    const int b  = bh >> 4;
    const int h  = bh & 15;
    const int h0 = h * 64;
    const size_t rowBase = (size_t)b * SEQ * D_MODEL;
    const int qw0 = qw * 32;
    const int ktMax = qw >> 1;          // last K-tile (only one needing mask)

    // VT staging source coords (dest is linear lane*16B per call)
    const int vdG = lane >> 3;          // 0..7 (= d&7 for every call)
    const int vsw = ((lane & 7) * 8) ^ (vdG << 3);
    const u16* vtRow0 = VTg + ((size_t)(bh * 64 + vdG)) * SEQ + vsw;

    const float SCL = 0.18033688011112042f;   // 0.125 * log2(e)

    // ---- Q fragments straight from global: B-frag [n=q=ln][k=qd*8+e] ----
    bf16x8 qf[2][2];
#pragma unroll
    for (int i = 0; i < 2; ++i)
#pragma unroll
        for (int ks = 0; ks < 2; ++ks)
            qf[i][ks] = *(const bf16x8*)(Qg + rowBase
                + (size_t)(qw0 + i * 16 + ln) * D_MODEL + h0 + ks * 32 + qd * 8);

    float m_run[2], l_run[2];
#pragma unroll
    for (int i = 0; i < 2; ++i) { m_run[i] = -30000.0f; l_run[i] = 0.f; }
    f32x4 oacc[2][4] = {};

    for (int kt = 0; kt <= ktMax; ++kt) {
        __syncthreads();                 // prev iter's Vsh/Psh reads done
        // ---- stage VT tile (64d x 64s) async; source col pre-swizzled ----
        {
            const u16* vbase = vtRow0 + kt * 64;
#pragma unroll
            for (int p = 0; p < 8; ++p)
                gload_lds16(vbase + (size_t)(p * 8) * SEQ, &Vsh[p * 512]);
        }

        // ---- S^T = K Q^T (K fragments straight from global) ----
        f32x4 sacc[4][2] = {};
#pragma unroll
        for (int ks = 0; ks < 2; ++ks) {
            bf16x8 kf[4];
#pragma unroll
            for (int j = 0; j < 4; ++j)
                kf[j] = *(const bf16x8*)(Kg + rowBase
                    + (size_t)(kt * 64 + j * 16 + ln) * D_MODEL + h0 + ks * 32 + qd * 8);
            __builtin_amdgcn_s_setprio(1);
#pragma unroll
            for (int j = 0; j < 4; ++j)
#pragma unroll
                for (int i = 0; i < 2; ++i)
                    sacc[j][i] = __builtin_amdgcn_mfma_f32_16x16x32_bf16(
                        kf[j], qf[i][ks], sacc[j][i], 0, 0, 0);
            __builtin_amdgcn_s_setprio(0);
        }

        // ---- scale to log2 domain (+ mask on the diagonal tile only) ----
        if (kt == ktMax) {
#pragma unroll
            for (int j = 0; j < 4; ++j)
#pragma unroll
                for (int r = 0; r < 4; ++r) {
                    const int kpos = kt * 64 + j * 16 + qd * 4 + r;
#pragma unroll
                    for (int i = 0; i < 2; ++i) {
                        const int qpos = qw0 + i * 16 + ln;
                        float s = sacc[j][i][r] * SCL;
                        sacc[j][i][r] = (kpos > qpos) ? -30000.0f : s;
                    }
                }
        } else {
#pragma unroll
            for (int j = 0; j < 4; ++j)
#pragma unroll
                for (int i = 0; i < 2; ++i)
#pragma unroll
                    for (int r = 0; r < 4; ++r)
                        sacc[j][i][r] *= SCL;
        }

        // ---- online softmax (log2 domain, lane-local) ----
        float mx[2];
#pragma unroll
        for (int i = 0; i < 2; ++i) {
            float m0 = sacc[0][i][0];
#pragma unroll
            for (int j = 0; j < 4; ++j)
#pragma unroll
                for (int r = 0; r < 4; ++r) m0 = fmaxf(m0, sacc[j][i][r]);
            m0 = fmaxf(m0, __shfl_xor(m0, 16));
            m0 = fmaxf(m0, __shfl_xor(m0, 32));
            mx[i] = m0;
        }

        // defer-max: skip rescale when max growth <= 8 (p <= 2^8)
        const bool grow = !(__all((mx[0] <= m_run[0] + 8.f) &&
                                  (mx[1] <= m_run[1] + 8.f)));
        if (grow) {
#pragma unroll
            for (int i = 0; i < 2; ++i) {
                const float mo = m_run[i];
                const float mn = fmaxf(mo, mx[i]);
                const float alpha = EXP2_FAST(mo - mn);
                m_run[i] = mn;
                l_run[i] *= alpha;
#pragma unroll
                for (int r = 0; r < 4; ++r) {
                    const float ar = __shfl(alpha, qd * 4 + r);
#pragma unroll
                    for (int j = 0; j < 4; ++j) oacc[i][j][r] *= ar;
                }
            }
        }

#pragma unroll
        for (int i = 0; i < 2; ++i) {
            const float mn = m_run[i];
            float rs = 0.f;
#pragma unroll
            for (int j = 0; j < 4; ++j) {
                u16 tp[4];
#pragma unroll
                for (int r = 0; r < 4; ++r) {
                    float p = EXP2_FAST(sacc[j][i][r] - mn);
                    rs += p;
                    tp[r] = f2bf_trunc(p);
                }
                uint2 w;
                w.x = (uint32_t)tp[0] | ((uint32_t)tp[1] << 16);
                w.y = (uint32_t)tp[2] | ((uint32_t)tp[3] << 16);
                *(uint2*)&Psh[(i * 16 + ln) * 64 + ((j * 16 + qd * 4) ^ psw)] = w;
            }
            rs += __shfl_xor(rs, 16);
            rs += __shfl_xor(rs, 32);
            l_run[i] += rs;
        }

        __syncthreads();                 // VT staged (vmcnt) + P visible

        // ---- O += P V : all-vector LDS reads ----
#pragma unroll
        for (int ks = 0; ks < 2; ++ks) {
            bf16x8 pa[2];                // A-frags of P: row = q = i*16+ln
#pragma unroll
            for (int i = 0; i < 2; ++i)
                pa[i] = *(const bf16x8*)&Psh[(i * 16 + ln) * 64
                                             + ((ks * 32 + qd * 8) ^ psw)];
            __builtin_amdgcn_s_setprio(1);
#pragma unroll
            for (int j = 0; j < 4; ++j) {
                const int d = j * 16 + ln;
                const bf16x8 vb = *(const bf16x8*)&Vsh[d * 64
                    + ((ks * 32 + qd * 8) ^ ((ln & 7) << 3))];
#pragma unroll
                for (int i = 0; i < 2; ++i)
                    oacc[i][j] = __builtin_amdgcn_mfma_f32_16x16x32_bf16(
                        pa[i], vb, oacc[i][j], 0, 0, 0);
            }
            __builtin_amdgcn_s_setprio(0);
        }
    }

    // ---- epilogue: O / l  (l lives at lane ln'=qd*4+r, shuffle it in) ----
#pragma unroll
    for (int i = 0; i < 2; ++i)
#pragma unroll
        for (int r = 0; r < 4; ++r) {
            const float lr = __shfl(l_run[i], qd * 4 + r);
            const float inv = 1.f / lr;
            const int qrow = qw0 + i * 16 + qd * 4 + r;
            u16* orow = Og + rowBase + (size_t)qrow * D_MODEL + h0 + ln;
#pragma unroll
            for (int j = 0; j < 4; ++j)
                orow[j * 16] = f2bf(oacc[i][j][r] * inv);
        }
}

// ---------------------------------------------------------------------------
static inline bool ranges_overlap(const void* a, size_t an, const void* b, size_t bn) {
    uintptr_t x0 = (uintptr_t)a, x1 = x0 + an;
    uintptr_t y0 = (uintptr_t)b, y1 = y0 + bn;
    return x0 < y1 && y0 < x1;
}

extern "C" void kernel_launch(void* const* d_in, const int* in_sizes, int n_in,
                              void* d_out, int out_size, void* d_ws, size_t ws_size,
                              hipStream_t stream)
{
    int e = 0;
    const int expect[9] = { 8388608, 1048576, 1024, 1048576, 1024,
                            1048576, 1024, 1048576, 1024 };
    if (n_in != 9) e = 59;
    if (!e) for (int i = 0; i < 9; ++i)
        if (in_sizes[i] != expect[i]) { e = 60 + i; break; }
    if (!e && out_size != (int)NXE) e = 53;
    if (!e && ranges_overlap(d_ws, ws_size, d_out, (size_t)out_size * 4)) e = 55;

    const size_t NX = NXE;
    const size_t NW = (size_t)D_MODEL * D_MODEL;
    const size_t NB = D_MODEL;

    // ws need: flag(64) + 4 weights + 4 biases + K + V = 40.0 MB (proven safe r7/r8).
    const size_t need = (64 + 4 * NW + 4 * NB + 2 * NX) * 2;
    if (!e && ws_size < need) e = 50;
    if (e) { diag_write<<<2048, 256, 0, stream>>>((float*)d_out, ldexpf(1.0f, e)); return; }

    // ws layout (u16 elems): flag | Wq Wk Wv Wo | bq bk bv bo | K | V
    u16* ws   = (u16*)d_ws;
    int* flag = (int*)ws;
    u16* Wqb  = ws + 64;
    u16* Wkb  = Wqb + NW;
    u16* Wvb  = Wkb + NW;
    u16* Wob  = Wvb + NW;
    u16* bqb  = Wob + NW;
    u16* bkb  = bqb + NB;
    u16* bvb  = bkb + NB;
    u16* bob  = bvb + NB;
    u16* Kw   = bob + NB;
    u16* Vw   = Kw  + NX;

    // Region lifetimes:
    //   d_out lower 16MB: xb (dead after gemm_qkv) -> VT (dead after flash)
    //   d_out upper 16MB: Qw (dead after flash)
    //   ws Vw: V (dead after transpose_v) -> Ow (attention output)
    //   gemm_final reads Ow (ws), writes fp32 DIRECTLY to d_out (no memcpy).
    u16* xb  = (u16*)d_out;          // x_bf16; dead after QKV gemm
    u16* Qw  = xb + NX;              // Q plane (upper half)
    u16* VTw = xb;                   // V^T reuses lower half
    u16* Ow  = Vw;                   // attention out over dead V plane

    detect_dtype<<<1, 256, 0, stream>>>((const u16*)d_in[0], flag);

    CvtArgs ca;
    const void* srcs[9] = { d_in[0], d_in[1], d_in[3], d_in[5], d_in[7],
                            d_in[2], d_in[4], d_in[6], d_in[8] };
    u16* dsts[9] = { xb, Wqb, Wkb, Wvb, Wob, bqb, bkb, bvb, bob };
    int  ns[9]   = { (int)NX, (int)NW, (int)NW, (int)NW, (int)NW,
                     (int)NB, (int)NB, (int)NB, (int)NB };
    for (int i = 0; i < 9; ++i) { ca.src[i] = srcs[i]; ca.dst[i] = dsts[i]; ca.n[i] = ns[i]; }
    cvt_all<<<dim3((unsigned)((NX + 2047) / 2048), 9), 256, 0, stream>>>(ca, flag);

    gemm_qkv<<<dim3(MTOT / 128, D_MODEL / 128, 3), 256, 0, stream>>>(
        xb, Wqb, Wkb, Wvb, bqb, bkb, bvb, Qw, Kw, Vw, MTOT, D_MODEL, D_MODEL);

    transpose_v<<<dim3(SEQ / 64, BATCH * NHEAD), 256, 0, stream>>>(Vw, VTw);

    flash_attn<<<dim3(SEQ / 32, BATCH * NHEAD), 64, 0, stream>>>(Qw, Kw, VTw, Ow);

    gemm_final_f32<<<dim3(MTOT / 128, D_MODEL / 128), 256, 0, stream>>>(
        Ow, Wob, bob, (float*)d_out, MTOT, D_MODEL, D_MODEL);
}

// Round 10
// 332.901 us; speedup vs baseline: 1.1272x; 1.0038x over previous
//
#include <hip/hip_runtime.h>
#include <cstdint>
#include <cmath>

typedef unsigned short u16;
typedef __attribute__((ext_vector_type(4))) float f32x4;
typedef __attribute__((ext_vector_type(8))) short bf16x8;

#define D_MODEL 1024
#define SEQ     2048
#define BATCH   4
#define NHEAD   16
#define MTOT    (BATCH*SEQ)      /* 8192 rows */
#define NXE     ((size_t)MTOT * D_MODEL)   /* 8,388,608 elems per plane */

static_assert(sizeof(bf16x8) == 16, "frag size");

__device__ __forceinline__ float bf2f(u16 u) {
    union { uint32_t i; float f; } v; v.i = ((uint32_t)u) << 16; return v.f;
}
__device__ __forceinline__ u16 f2bf(float x) {
    union { float f; uint32_t i; } v; v.f = x;
    uint32_t r = (v.i + 0x7FFFu + ((v.i >> 16) & 1u)) >> 16;   // RNE
    return (u16)r;
}
__device__ __forceinline__ u16 f2bf_trunc(float x) {          // cheap: P only
    union { float f; uint32_t i; } v; v.f = x;
    return (u16)(v.i >> 16);
}

// exp2 that lowers to a bare v_exp_f32 (HIP has no __exp2f; glibc macro clash)
#if defined(__has_builtin)
#if __has_builtin(__builtin_amdgcn_exp2f)
#define EXP2_FAST(x) __builtin_amdgcn_exp2f(x)
#endif
#endif
#ifndef EXP2_FAST
#define EXP2_FAST(x) exp2f(x)
#endif

typedef const __attribute__((address_space(1))) void* gptr_t;
typedef __attribute__((address_space(3))) void* sptr_t;
__device__ __forceinline__ void gload_lds16(const void* g, void* l) {
    __builtin_amdgcn_global_load_lds((gptr_t)g, (sptr_t)l, 16, 0, 0);
}

// extract u16 element e (compile-time const after unroll) from a uint4
__device__ __forceinline__ u16 u4get(const uint4& v, int e) {
    const uint32_t w = ((e >> 1) == 0) ? v.x : ((e >> 1) == 1) ? v.y
                     : ((e >> 1) == 2) ? v.z : v.w;
    return (u16)((e & 1) ? (w >> 16) : (w & 0xFFFFu));
}

// ---------------------------------------------------------------------------
// Precondition-failure flood: d_out is fp32; absmax report encodes 2^e.
// ---------------------------------------------------------------------------
__global__ __launch_bounds__(256) void diag_write(float* __restrict__ out, float v) {
    size_t i = (size_t)blockIdx.x * 256 + threadIdx.x;
    for (; i < NXE; i += (size_t)gridDim.x * 256) out[i] = v;
}

// ---------------------------------------------------------------------------
// Dtype sniffer (validated r3/r5/r6: inputs are fp32 -> flag=0).
// ---------------------------------------------------------------------------
__global__ void detect_dtype(const u16* __restrict__ x, int* __restrict__ flag) {
    __shared__ int cnt;
    if (threadIdx.x == 0) cnt = 0;
    __syncthreads();
    int c = 0;
#pragma unroll
    for (int k = 0; k < 16; ++k) {
        u16 e = x[2 * (threadIdx.x * 16 + k)];
        int ex = (e >> 7) & 0xFF;
        if (e == 0 || (ex >= 100 && ex <= 140)) ++c;
    }
    atomicAdd(&cnt, c);
    __syncthreads();
    if (threadIdx.x == 0) *flag = (cnt >= 3500) ? 1 : 0;
}

// ---------------------------------------------------------------------------
// Normalize inputs to bf16 planes (fp32 -> RNE downconvert; bf16 -> copy).
// ---------------------------------------------------------------------------
struct CvtArgs { const void* src[9]; u16* dst[9]; int n[9]; };

__global__ __launch_bounds__(256) void cvt_all(CvtArgs a, const int* __restrict__ flag) {
    const int seg = blockIdx.y;
    const int n = a.n[seg];
    const int i = (blockIdx.x * 256 + threadIdx.x) * 8;
    if (i >= n) return;
    u16* d = a.dst[seg] + i;
    if (*flag) {
        *(uint4*)d = *(const uint4*)((const u16*)a.src[seg] + i);
    } else {
        const float* s = (const float*)a.src[seg] + i;
        u16 tmp[8];
#pragma unroll
        for (int k = 0; k < 8; ++k) tmp[k] = f2bf(s[k]);
        *(uint4*)d = *(uint4*)tmp;
    }
}

// ---------------------------------------------------------------------------
// MFMA GEMM (m97 structure, 128x128, BK=32) — correctness proven (r6/r7/r8).
// ---------------------------------------------------------------------------
template <typename OutT>
__device__ __forceinline__ void gemm_body(
    const u16* __restrict__ A, const u16* __restrict__ W,
    const u16* __restrict__ bias, OutT* __restrict__ C,
    int M, int N, int K)
{
    __shared__ __align__(16) u16 As[128 * 32];
    __shared__ __align__(16) u16 Bs[128 * 32];

    const int t    = threadIdx.x;
    const int wave = t >> 6;
    const int ln   = t & 15;
    const int qd   = (t >> 4) & 3;
    const int m0   = blockIdx.x * 128;
    const int n0   = blockIdx.y * 128;
    const int wm   = (wave >> 1) * 64;
    const int wn   = (wave & 1) * 64;

    const int srow = t >> 2;
    const int scol = (t & 3) * 8;
    const u16* gA = A + (size_t)(m0 + srow) * K + scol;
    const u16* gB = W + (size_t)(n0 + srow) * K + scol;
    u16* lA = &As[wave * 512];
    u16* lB = &Bs[wave * 512];

    f32x4 acc[4][4] = {};

    for (int k0 = 0; k0 < K; k0 += 32) {
        __syncthreads();
        gload_lds16(gA + k0,                   lA);
        gload_lds16(gA + (size_t)64 * K + k0,  lA + 2048);
        gload_lds16(gB + k0,                   lB);
        gload_lds16(gB + (size_t)64 * K + k0,  lB + 2048);
        __syncthreads();

        bf16x8 af[4], bfr[4];
#pragma unroll
        for (int i = 0; i < 4; ++i)
            af[i] = *(const bf16x8*)&As[(wm + i * 16 + ln) * 32 + qd * 8];
#pragma unroll
        for (int j = 0; j < 4; ++j)
            bfr[j] = *(const bf16x8*)&Bs[(wn + j * 16 + ln) * 32 + qd * 8];
#pragma unroll
        for (int i = 0; i < 4; ++i)
#pragma unroll
            for (int j = 0; j < 4; ++j)
                acc[i][j] = __builtin_amdgcn_mfma_f32_16x16x32_bf16(
                    af[i], bfr[j], acc[i][j], 0, 0, 0);
    }

    float bv[4];
#pragma unroll
    for (int j = 0; j < 4; ++j) bv[j] = bf2f(bias[n0 + wn + j * 16 + ln]);

#pragma unroll
    for (int i = 0; i < 4; ++i)
#pragma unroll
        for (int r = 0; r < 4; ++r) {
            int row = m0 + wm + i * 16 + qd * 4 + r;
            OutT* crow = C + (size_t)row * N + n0 + wn + ln;
#pragma unroll
            for (int j = 0; j < 4; ++j) {
                float v = acc[i][j][r] + bv[j];
                if constexpr (sizeof(OutT) == 2) crow[j * 16] = f2bf(v);
                else                             crow[j * 16] = v;
            }
        }
}

__global__ __launch_bounds__(256) void gemm_qkv(
    const u16* __restrict__ A,
    const u16* __restrict__ W0, const u16* __restrict__ W1, const u16* __restrict__ W2,
    const u16* __restrict__ b0, const u16* __restrict__ b1, const u16* __restrict__ b2,
    u16* __restrict__ C0, u16* __restrict__ C1, u16* __restrict__ C2,
    int M, int N, int K)
{
    const u16* W; const u16* bias; u16* C;
    if (blockIdx.z == 0)      { W = W0; bias = b0; C = C0; }
    else if (blockIdx.z == 1) { W = W1; bias = b1; C = C1; }
    else                      { W = W2; bias = b2; C = C2; }
    gemm_body<u16>(A, W, bias, C, M, N, K);
}

__global__ __launch_bounds__(256) void gemm_final_f32(
    const u16* __restrict__ A, const u16* __restrict__ W,
    const u16* __restrict__ bias, float* __restrict__ C, int M, int N, int K)
{
    gemm_body<float>(A, W, bias, C, M, N, K);
}

// ---------------------------------------------------------------------------
// V transpose: V[b*S+s][h*64+d]  ->  VT[(bh*64+d)][s]   (per-head d-major).
// 64x64 tiles through LDS; ~32 MB total traffic (~6 us). Proven correct (r12).
// ---------------------------------------------------------------------------
__global__ __launch_bounds__(256) void transpose_v(
    const u16* __restrict__ V, u16* __restrict__ VT)
{
    __shared__ u16 T[64][72];           // +8 pad: 144 B row stride (16B-aligned)
    const int st = blockIdx.x;          // s-tile (0..31)
    const int bh = blockIdx.y;          // 0..63
    const int b  = bh >> 4;
    const int h  = bh & 15;
    const int t  = threadIdx.x;

    const int sr = t >> 2;              // local s row 0..63
    const int dc = (t & 3) * 16;        // d chunk 0,16,32,48
    const u16* src = V + ((size_t)b * SEQ + st * 64 + sr) * D_MODEL + h * 64 + dc;
    const uint4 a0 = *(const uint4*)src;
    const uint4 a1 = *(const uint4*)(src + 8);
#pragma unroll
    for (int e = 0; e < 8; ++e) T[dc + e][sr]     = u4get(a0, e);
#pragma unroll
    for (int e = 0; e < 8; ++e) T[dc + 8 + e][sr] = u4get(a1, e);
    __syncthreads();

    const int d  = t >> 2;              // 0..63
    const int sc = (t & 3) * 16;        // 0,16,32,48
    u16* dst = VT + ((size_t)bh * 64 + d) * SEQ + st * 64 + sc;
    *(uint4*)dst       = *(const uint4*)&T[d][sc];
    *(uint4*)(dst + 8) = *(const uint4*)&T[d][sc + 8];
}

// ---------------------------------------------------------------------------
// Flash attention, causal — round 19: KT-SPLIT ACROSS 2 WAVES PER BLOCK.
//   Block (x, bh) owns ONE 32-row q-tile; wave w processes kt = w, w+2, ...
//   (strided: all blocks of a plane stay kt-synchronized -> r14's low-fetch
//   property preserved; R7's desync lesson respected).  Online softmax is
//   associative: each wave keeps private (m, l, O_unnorm); ONE LDS merge at
//   the end.  Max per-wave length 32 -> 16 kt-iters (makespan was bound by
//   32-iter blocks finishing alone: occupancy 14.5%).  8192 waves over 12
//   resident/CU (24 KB LDS: private Vsh+Psh per wave) -> backfill queue
//   sustains residency instead of decaying.
//   NO __syncthreads in the loop (waves fully independent, private buffers).
//   Intra-wave hazards via inline-asm waits + sched_barrier (rule #18):
//     - lgkmcnt(0) before re-staging own Vsh (prev PV reads done)
//     - vmcnt(0) before PV (own global_load_lds landed)
//   Retained: swapped QK^T lane-local softmax, exp2 domain, defer-max,
//   s_setprio, swizzled VT staging, grid balance mapping.
// Grid: x = 64, y = 64 (b*h); 128 threads (2 waves); LDS 24 KB.
// ---------------------------------------------------------------------------
__global__ __launch_bounds__(128) void flash_attn(
    const u16* __restrict__ Qg, const u16* __restrict__ Kg,
    const u16* __restrict__ VTg, u16* __restrict__ Og)
{
    __shared__ __align__(16) u16 Vsh[2][64 * 64];   // per-wave VT tile, swizzled
    __shared__ __align__(16) u16 Psh[2][32 * 64];   // per-wave P

    const int wv   = threadIdx.x >> 6;  // wave 0/1
    const int lane = threadIdx.x & 63;
    const int ln   = lane & 15;
    const int qd   = lane >> 4;
    const int psw  = (ln & 7) << 3;     // P swizzle (u16 elems)

    const int bh = blockIdx.y;
    const int qw = (63 - (int)blockIdx.x + bh) & 63;   // balance fix (r11)
    const int b  = bh >> 4;
    const int h  = bh & 15;
    const int h0 = h * 64;
    const size_t rowBase = (size_t)b * SEQ * D_MODEL;
    const int qw0 = qw * 32;
    const int ktMax = qw >> 1;          // last K-tile (only one needing mask)

    u16* VshW = &Vsh[wv][0];
    u16* P    = &Psh[wv][0];

    // VT staging source coords (dest is linear lane*16B per call)
    const int vdG = lane >> 3;          // 0..7 (= d&7 for every call)
    const int vsw = ((lane & 7) * 8) ^ (vdG << 3);
    const u16* vtRow0 = VTg + ((size_t)(bh * 64 + vdG)) * SEQ + vsw;

    const float SCL = 0.18033688011112042f;   // 0.125 * log2(e)

    // ---- Q fragments straight from global: B-frag [n=q=ln][k=qd*8+e] ----
    bf16x8 qf[2][2];
#pragma unroll
    for (int i = 0; i < 2; ++i)
#pragma unroll
        for (int ks = 0; ks < 2; ++ks)
            qf[i][ks] = *(const bf16x8*)(Qg + rowBase
                + (size_t)(qw0 + i * 16 + ln) * D_MODEL + h0 + ks * 32 + qd * 8);

    float m_run[2], l_run[2];
#pragma unroll
    for (int i = 0; i < 2; ++i) { m_run[i] = -30000.0f; l_run[i] = 0.f; }
    f32x4 oacc[2][4] = {};

    for (int kt = wv; kt <= ktMax; kt += 2) {
        // own prior PV LDS reads complete before overwriting own Vsh
        asm volatile("s_waitcnt lgkmcnt(0)" ::: "memory");
        __builtin_amdgcn_sched_barrier(0);

        // ---- stage VT tile (64d x 64s) async; source col pre-swizzled ----
        {
            const u16* vbase = vtRow0 + kt * 64;
#pragma unroll
            for (int p = 0; p < 8; ++p)
                gload_lds16(vbase + (size_t)(p * 8) * SEQ, &VshW[p * 512]);
        }

        // ---- S^T = K Q^T (K fragments straight from global) ----
        f32x4 sacc[4][2] = {};
#pragma unroll
        for (int ks = 0; ks < 2; ++ks) {
            bf16x8 kf[4];
#pragma unroll
            for (int j = 0; j < 4; ++j)
                kf[j] = *(const bf16x8*)(Kg + rowBase
                    + (size_t)(kt * 64 + j * 16 + ln) * D_MODEL + h0 + ks * 32 + qd * 8);
            __builtin_amdgcn_s_setprio(1);
#pragma unroll
            for (int j = 0; j < 4; ++j)
#pragma unroll
                for (int i = 0; i < 2; ++i)
                    sacc[j][i] = __builtin_amdgcn_mfma_f32_16x16x32_bf16(
                        kf[j], qf[i][ks], sacc[j][i], 0, 0, 0);
            __builtin_amdgcn_s_setprio(0);
        }

        // ---- scale to log2 domain (+ mask on the diagonal tile only) ----
        if (kt == ktMax) {
#pragma unroll
            for (int j = 0; j < 4; ++j)
#pragma unroll
                for (int r = 0; r < 4; ++r) {
                    const int kpos = kt * 64 + j * 16 + qd * 4 + r;
#pragma unroll
                    for (int i = 0; i < 2; ++i) {
                        const int qpos = qw0 + i * 16 + ln;
                        float s = sacc[j][i][r] * SCL;
                        sacc[j][i][r] = (kpos > qpos) ? -30000.0f : s;
                    }
                }
        } else {
#pragma unroll
            for (int j = 0; j < 4; ++j)
#pragma unroll
                for (int i = 0; i < 2; ++i)
#pragma unroll
                    for (int r = 0; r < 4; ++r)
                        sacc[j][i][r] *= SCL;
        }

        // ---- online softmax (log2 domain, lane-local) ----
        float mx[2];
#pragma unroll
        for (int i = 0; i < 2; ++i) {
            float m0 = sacc[0][i][0];
#pragma unroll
            for (int j = 0; j < 4; ++j)
#pragma unroll
                for (int r = 0; r < 4; ++r) m0 = fmaxf(m0, sacc[j][i][r]);
            m0 = fmaxf(m0, __shfl_xor(m0, 16));
            m0 = fmaxf(m0, __shfl_xor(m0, 32));
            mx[i] = m0;
        }

        // defer-max: skip rescale when max growth <= 8 (p <= 2^8)
        const bool grow = !(__all((mx[0] <= m_run[0] + 8.f) &&
                                  (mx[1] <= m_run[1] + 8.f)));
        if (grow) {
#pragma unroll
            for (int i = 0; i < 2; ++i) {
                const float mo = m_run[i];
                const float mn = fmaxf(mo, mx[i]);
                const float alpha = EXP2_FAST(mo - mn);
                m_run[i] = mn;
                l_run[i] *= alpha;
#pragma unroll
                for (int r = 0; r < 4; ++r) {
                    const float ar = __shfl(alpha, qd * 4 + r);
#pragma unroll
                    for (int j = 0; j < 4; ++j) oacc[i][j][r] *= ar;
                }
            }
        }

#pragma unroll
        for (int i = 0; i < 2; ++i) {
            const float mn = m_run[i];
            float rs = 0.f;
#pragma unroll
            for (int j = 0; j < 4; ++j) {
                u16 tp[4];
#pragma unroll
                for (int r = 0; r < 4; ++r) {
                    float p = EXP2_FAST(sacc[j][i][r] - mn);
                    rs += p;
                    tp[r] = f2bf_trunc(p);
                }
                uint2 w;
                w.x = (uint32_t)tp[0] | ((uint32_t)tp[1] << 16);
                w.y = (uint32_t)tp[2] | ((uint32_t)tp[3] << 16);
                *(uint2*)&P[(i * 16 + ln) * 64 + ((j * 16 + qd * 4) ^ psw)] = w;
            }
            rs += __shfl_xor(rs, 16);
            rs += __shfl_xor(rs, 32);
            l_run[i] += rs;
        }

        // own stage landed before PV reads Vsh (compiler can't see gload->LDS)
        asm volatile("s_waitcnt vmcnt(0)" ::: "memory");
        __builtin_amdgcn_sched_barrier(0);

        // ---- O += P V : all-vector LDS reads ----
#pragma unroll
        for (int ks = 0; ks < 2; ++ks) {
            bf16x8 pa[2];                // A-frags of P: row = q = i*16+ln
#pragma unroll
            for (int i = 0; i < 2; ++i)
                pa[i] = *(const bf16x8*)&P[(i * 16 + ln) * 64
                                           + ((ks * 32 + qd * 8) ^ psw)];
            __builtin_amdgcn_s_setprio(1);
#pragma unroll
            for (int j = 0; j < 4; ++j) {
                const int d = j * 16 + ln;
                const bf16x8 vb = *(const bf16x8*)&VshW[d * 64
                    + ((ks * 32 + qd * 8) ^ ((ln & 7) << 3))];
#pragma unroll
                for (int i = 0; i < 2; ++i)
                    oacc[i][j] = __builtin_amdgcn_mfma_f32_16x16x32_bf16(
                        pa[i], vb, oacc[i][j], 0, 0, 0);
            }
            __builtin_amdgcn_s_setprio(0);
        }
    }

    // ---- cross-wave merge: wave1 -> LDS; wave0 merges + writes output ----
    float* exO  = (float*)&Vsh[1][0];   // 2048 f32: wave1 unnormalized O
    float* exML = (float*)&Psh[1][0];   // m[32] | l[32]
    if (wv == 1) {
        if (qd == 0) {
#pragma unroll
            for (int i = 0; i < 2; ++i) {
                exML[i * 16 + ln]      = m_run[i];
                exML[32 + i * 16 + ln] = l_run[i];
            }
        }
#pragma unroll
        for (int i = 0; i < 2; ++i)
#pragma unroll
            for (int j = 0; j < 4; ++j)
#pragma unroll
                for (int r = 0; r < 4; ++r)
                    exO[(i * 16 + qd * 4 + r) * 64 + j * 16 + ln] = oacc[i][j][r];
    }
    __syncthreads();
    if (wv == 0) {
#pragma unroll
        for (int i = 0; i < 2; ++i)
#pragma unroll
            for (int r = 0; r < 4; ++r) {
                const int row = i * 16 + qd * 4 + r;
                const float m0r = __shfl(m_run[i], qd * 4 + r);
                const float l0r = __shfl(l_run[i], qd * 4 + r);
                const float m1r = exML[row];
                const float l1r = exML[32 + row];
                const float mm  = fmaxf(m0r, m1r);
                const float a0  = EXP2_FAST(m0r - mm);
                const float a1  = EXP2_FAST(m1r - mm);
                const float inv = 1.f / (a0 * l0r + a1 * l1r);
                const int qrow = qw0 + row;
                u16* orow = Og + rowBase + (size_t)qrow * D_MODEL + h0 + ln;
#pragma unroll
                for (int j = 0; j < 4; ++j)
                    orow[j * 16] = f2bf((a0 * oacc[i][j][r]
                                         + a1 * exO[row * 64 + j * 16 + ln]) * inv);
            }
    }
}

// ---------------------------------------------------------------------------
static inline bool ranges_overlap(const void* a, size_t an, const void* b, size_t bn) {
    uintptr_t x0 = (uintptr_t)a, x1 = x0 + an;
    uintptr_t y0 = (uintptr_t)b, y1 = y0 + bn;
    return x0 < y1 && y0 < x1;
}

extern "C" void kernel_launch(void* const* d_in, const int* in_sizes, int n_in,
                              void* d_out, int out_size, void* d_ws, size_t ws_size,
                              hipStream_t stream)
{
    int e = 0;
    const int expect[9] = { 8388608, 1048576, 1024, 1048576, 1024,
                            1048576, 1024, 1048576, 1024 };
    if (n_in != 9) e = 59;
    if (!e) for (int i = 0; i < 9; ++i)
        if (in_sizes[i] != expect[i]) { e = 60 + i; break; }
    if (!e && out_size != (int)NXE) e = 53;
    if (!e && ranges_overlap(d_ws, ws_size, d_out, (size_t)out_size * 4)) e = 55;

    const size_t NX = NXE;
    const size_t NW = (size_t)D_MODEL * D_MODEL;
    const size_t NB = D_MODEL;

    // ws need: flag(64) + 4 weights + 4 biases + K + V = 40.0 MB (proven safe r7/r8).
    const size_t need = (64 + 4 * NW + 4 * NB + 2 * NX) * 2;
    if (!e && ws_size < need) e = 50;
    if (e) { diag_write<<<2048, 256, 0, stream>>>((float*)d_out, ldexpf(1.0f, e)); return; }

    // ws layout (u16 elems): flag | Wq Wk Wv Wo | bq bk bv bo | K | V
    u16* ws   = (u16*)d_ws;
    int* flag = (int*)ws;
    u16* Wqb  = ws + 64;
    u16* Wkb  = Wqb + NW;
    u16* Wvb  = Wkb + NW;
    u16* Wob  = Wvb + NW;
    u16* bqb  = Wob + NW;
    u16* bkb  = bqb + NB;
    u16* bvb  = bkb + NB;
    u16* bob  = bvb + NB;
    u16* Kw   = bob + NB;
    u16* Vw   = Kw  + NX;

    // Region lifetimes:
    //   d_out lower 16MB: xb (dead after gemm_qkv) -> VT (dead after flash)
    //   d_out upper 16MB: Qw (dead after flash)
    //   ws Vw: V (dead after transpose_v) -> Ow (attention output)
    //   gemm_final reads Ow (ws), writes fp32 DIRECTLY to d_out (no memcpy).
    u16* xb  = (u16*)d_out;          // x_bf16; dead after QKV gemm
    u16* Qw  = xb + NX;              // Q plane (upper half)
    u16* VTw = xb;                   // V^T reuses lower half
    u16* Ow  = Vw;                   // attention out over dead V plane

    detect_dtype<<<1, 256, 0, stream>>>((const u16*)d_in[0], flag);

    CvtArgs ca;
    const void* srcs[9] = { d_in[0], d_in[1], d_in[3], d_in[5], d_in[7],
                            d_in[2], d_in[4], d_in[6], d_in[8] };
    u16* dsts[9] = { xb, Wqb, Wkb, Wvb, Wob, bqb, bkb, bvb, bob };
    int  ns[9]   = { (int)NX, (int)NW, (int)NW, (int)NW, (int)NW,
                     (int)NB, (int)NB, (int)NB, (int)NB };
    for (int i = 0; i < 9; ++i) { ca.src[i] = srcs[i]; ca.dst[i] = dsts[i]; ca.n[i] = ns[i]; }
    cvt_all<<<dim3((unsigned)((NX + 2047) / 2048), 9), 256, 0, stream>>>(ca, flag);

    gemm_qkv<<<dim3(MTOT / 128, D_MODEL / 128, 3), 256, 0, stream>>>(
        xb, Wqb, Wkb, Wvb, bqb, bkb, bvb, Qw, Kw, Vw, MTOT, D_MODEL, D_MODEL);

    transpose_v<<<dim3(SEQ / 64, BATCH * NHEAD), 256, 0, stream>>>(Vw, VTw);

    flash_attn<<<dim3(SEQ / 32, BATCH * NHEAD), 128, 0, stream>>>(Qw, Kw, VTw, Ow);

    gemm_final_f32<<<dim3(MTOT / 128, D_MODEL / 128), 256, 0, stream>>>(
        Ow, Wob, bob, (float*)d_out, MTOT, D_MODEL, D_MODEL);
}

// Round 11
// 322.624 us; speedup vs baseline: 1.1631x; 1.0319x over previous
//
#include <hip/hip_runtime.h>
#include <cstdint>
#include <cmath>

typedef unsigned short u16;
typedef __attribute__((ext_vector_type(4))) float f32x4;
typedef __attribute__((ext_vector_type(8))) short bf16x8;

#define D_MODEL 1024
#define SEQ     2048
#define BATCH   4
#define NHEAD   16
#define MTOT    (BATCH*SEQ)      /* 8192 rows */
#define NXE     ((size_t)MTOT * D_MODEL)   /* 8,388,608 elems per plane */

static_assert(sizeof(bf16x8) == 16, "frag size");

__device__ __forceinline__ float bf2f(u16 u) {
    union { uint32_t i; float f; } v; v.i = ((uint32_t)u) << 16; return v.f;
}
__device__ __forceinline__ u16 f2bf(float x) {
    union { float f; uint32_t i; } v; v.f = x;
    uint32_t r = (v.i + 0x7FFFu + ((v.i >> 16) & 1u)) >> 16;   // RNE
    return (u16)r;
}
__device__ __forceinline__ u16 f2bf_trunc(float x) {          // cheap: P only
    union { float f; uint32_t i; } v; v.f = x;
    return (u16)(v.i >> 16);
}

// exp2 that lowers to a bare v_exp_f32 (HIP has no __exp2f; glibc macro clash)
#if defined(__has_builtin)
#if __has_builtin(__builtin_amdgcn_exp2f)
#define EXP2_FAST(x) __builtin_amdgcn_exp2f(x)
#endif
#endif
#ifndef EXP2_FAST
#define EXP2_FAST(x) exp2f(x)
#endif

typedef const __attribute__((address_space(1))) void* gptr_t;
typedef __attribute__((address_space(3))) void* sptr_t;
__device__ __forceinline__ void gload_lds16(const void* g, void* l) {
    __builtin_amdgcn_global_load_lds((gptr_t)g, (sptr_t)l, 16, 0, 0);
}

// extract u16 element e (compile-time const after unroll) from a uint4
__device__ __forceinline__ u16 u4get(const uint4& v, int e) {
    const uint32_t w = ((e >> 1) == 0) ? v.x : ((e >> 1) == 1) ? v.y
                     : ((e >> 1) == 2) ? v.z : v.w;
    return (u16)((e & 1) ? (w >> 16) : (w & 0xFFFFu));
}

// ---------------------------------------------------------------------------
// Precondition-failure flood: d_out is fp32; absmax report encodes 2^e.
// ---------------------------------------------------------------------------
__global__ __launch_bounds__(256) void diag_write(float* __restrict__ out, float v) {
    size_t i = (size_t)blockIdx.x * 256 + threadIdx.x;
    for (; i < NXE; i += (size_t)gridDim.x * 256) out[i] = v;
}

// ---------------------------------------------------------------------------
// Dtype sniffer (validated r3/r5/r6: inputs are fp32 -> flag=0).
// ---------------------------------------------------------------------------
__global__ void detect_dtype(const u16* __restrict__ x, int* __restrict__ flag) {
    __shared__ int cnt;
    if (threadIdx.x == 0) cnt = 0;
    __syncthreads();
    int c = 0;
#pragma unroll
    for (int k = 0; k < 16; ++k) {
        u16 e = x[2 * (threadIdx.x * 16 + k)];
        int ex = (e >> 7) & 0xFF;
        if (e == 0 || (ex >= 100 && ex <= 140)) ++c;
    }
    atomicAdd(&cnt, c);
    __syncthreads();
    if (threadIdx.x == 0) *flag = (cnt >= 3500) ? 1 : 0;
}

// ---------------------------------------------------------------------------
// Normalize inputs to bf16 planes (fp32 -> RNE downconvert; bf16 -> copy).
// ---------------------------------------------------------------------------
struct CvtArgs { const void* src[9]; u16* dst[9]; int n[9]; };

__global__ __launch_bounds__(256) void cvt_all(CvtArgs a, const int* __restrict__ flag) {
    const int seg = blockIdx.y;
    const int n = a.n[seg];
    const int i = (blockIdx.x * 256 + threadIdx.x) * 8;
    if (i >= n) return;
    u16* d = a.dst[seg] + i;
    if (*flag) {
        *(uint4*)d = *(const uint4*)((const u16*)a.src[seg] + i);
    } else {
        const float* s = (const float*)a.src[seg] + i;
        u16 tmp[8];
#pragma unroll
        for (int k = 0; k < 8; ++k) tmp[k] = f2bf(s[k]);
        *(uint4*)d = *(uint4*)tmp;
    }
}

// ---------------------------------------------------------------------------
// MFMA GEMM — round 20: T3-minimum pipeline on the proven 128x128/BK=32
// skeleton.  Old body: { barrier; gload x4; barrier(vmcnt0 drain); compute }
// -> every tile's global latency fully exposed (nothing in flight during the
// drain).  New body: double-buffered LDS, stage tile t+1 BEFORE computing
// tile t, ONE barrier per K-step -> loads fly under ds_read+MFMA.
// Occupancy: VGPR-capped at 4 blocks/CU (116 VGPR), so LDS 16->32 KB is
// free (LDS cap 5 > VGPR cap 4).
// ---------------------------------------------------------------------------
template <typename OutT>
__device__ __forceinline__ void gemm_body(
    const u16* __restrict__ A, const u16* __restrict__ W,
    const u16* __restrict__ bias, OutT* __restrict__ C,
    int M, int N, int K)
{
    __shared__ __align__(16) u16 As[2][128 * 32];
    __shared__ __align__(16) u16 Bs[2][128 * 32];

    const int t    = threadIdx.x;
    const int wave = t >> 6;
    const int ln   = t & 15;
    const int qd   = (t >> 4) & 3;
    const int m0   = blockIdx.x * 128;
    const int n0   = blockIdx.y * 128;
    const int wm   = (wave >> 1) * 64;
    const int wn   = (wave & 1) * 64;

    const int srow = t >> 2;
    const int scol = (t & 3) * 8;
    const u16* gA = A + (size_t)(m0 + srow) * K + scol;
    const u16* gB = W + (size_t)(n0 + srow) * K + scol;

    f32x4 acc[4][4] = {};

    // prologue: stage k0 = 0 into buffer 0
    {
        u16* lA = &As[0][wave * 512];
        u16* lB = &Bs[0][wave * 512];
        gload_lds16(gA,                   lA);
        gload_lds16(gA + (size_t)64 * K,  lA + 2048);
        gload_lds16(gB,                   lB);
        gload_lds16(gB + (size_t)64 * K,  lB + 2048);
    }
    __syncthreads();               // vmcnt(0) drained -> buf0 ready

    int cur = 0;
    for (int k0 = 0; k0 < K; k0 += 32) {
        // ---- stage NEXT tile into the other buffer (flies under compute) ----
        if (k0 + 32 < K) {
            u16* lA = &As[cur ^ 1][wave * 512];
            u16* lB = &Bs[cur ^ 1][wave * 512];
            gload_lds16(gA + k0 + 32,                   lA);
            gload_lds16(gA + (size_t)64 * K + k0 + 32,  lA + 2048);
            gload_lds16(gB + k0 + 32,                   lB);
            gload_lds16(gB + (size_t)64 * K + k0 + 32,  lB + 2048);
        }

        // ---- compute current tile ----
        bf16x8 af[4], bfr[4];
#pragma unroll
        for (int i = 0; i < 4; ++i)
            af[i] = *(const bf16x8*)&As[cur][(wm + i * 16 + ln) * 32 + qd * 8];
#pragma unroll
        for (int j = 0; j < 4; ++j)
            bfr[j] = *(const bf16x8*)&Bs[cur][(wn + j * 16 + ln) * 32 + qd * 8];
#pragma unroll
        for (int i = 0; i < 4; ++i)
#pragma unroll
            for (int j = 0; j < 4; ++j)
                acc[i][j] = __builtin_amdgcn_mfma_f32_16x16x32_bf16(
                    af[i], bfr[j], acc[i][j], 0, 0, 0);

        __syncthreads();           // next loads landed + our ds_reads done
        cur ^= 1;
    }

    float bv[4];
#pragma unroll
    for (int j = 0; j < 4; ++j) bv[j] = bf2f(bias[n0 + wn + j * 16 + ln]);

#pragma unroll
    for (int i = 0; i < 4; ++i)
#pragma unroll
        for (int r = 0; r < 4; ++r) {
            int row = m0 + wm + i * 16 + qd * 4 + r;
            OutT* crow = C + (size_t)row * N + n0 + wn + ln;
#pragma unroll
            for (int j = 0; j < 4; ++j) {
                float v = acc[i][j][r] + bv[j];
                if constexpr (sizeof(OutT) == 2) crow[j * 16] = f2bf(v);
                else                             crow[j * 16] = v;
            }
        }
}

__global__ __launch_bounds__(256) void gemm_qkv(
    const u16* __restrict__ A,
    const u16* __restrict__ W0, const u16* __restrict__ W1, const u16* __restrict__ W2,
    const u16* __restrict__ b0, const u16* __restrict__ b1, const u16* __restrict__ b2,
    u16* __restrict__ C0, u16* __restrict__ C1, u16* __restrict__ C2,
    int M, int N, int K)
{
    const u16* W; const u16* bias; u16* C;
    if (blockIdx.z == 0)      { W = W0; bias = b0; C = C0; }
    else if (blockIdx.z == 1) { W = W1; bias = b1; C = C1; }
    else                      { W = W2; bias = b2; C = C2; }
    gemm_body<u16>(A, W, bias, C, M, N, K);
}

__global__ __launch_bounds__(256) void gemm_final_f32(
    const u16* __restrict__ A, const u16* __restrict__ W,
    const u16* __restrict__ bias, float* __restrict__ C, int M, int N, int K)
{
    gemm_body<float>(A, W, bias, C, M, N, K);
}

// ---------------------------------------------------------------------------
// V transpose: V[b*S+s][h*64+d]  ->  VT[(bh*64+d)][s]   (per-head d-major).
// 64x64 tiles through LDS; ~32 MB total traffic (~6 us). Proven correct (r12).
// ---------------------------------------------------------------------------
__global__ __launch_bounds__(256) void transpose_v(
    const u16* __restrict__ V, u16* __restrict__ VT)
{
    __shared__ u16 T[64][72];           // +8 pad: 144 B row stride (16B-aligned)
    const int st = blockIdx.x;          // s-tile (0..31)
    const int bh = blockIdx.y;          // 0..63
    const int b  = bh >> 4;
    const int h  = bh & 15;
    const int t  = threadIdx.x;

    const int sr = t >> 2;              // local s row 0..63
    const int dc = (t & 3) * 16;        // d chunk 0,16,32,48
    const u16* src = V + ((size_t)b * SEQ + st * 64 + sr) * D_MODEL + h * 64 + dc;
    const uint4 a0 = *(const uint4*)src;
    const uint4 a1 = *(const uint4*)(src + 8);
#pragma unroll
    for (int e = 0; e < 8; ++e) T[dc + e][sr]     = u4get(a0, e);
#pragma unroll
    for (int e = 0; e < 8; ++e) T[dc + 8 + e][sr] = u4get(a1, e);
    __syncthreads();

    const int d  = t >> 2;              // 0..63
    const int sc = (t & 3) * 16;        // 0,16,32,48
    u16* dst = VT + ((size_t)bh * 64 + d) * SEQ + st * 64 + sc;
    *(uint4*)dst       = *(const uint4*)&T[d][sc];
    *(uint4*)(dst + 8) = *(const uint4*)&T[d][sc + 8];
}

// ---------------------------------------------------------------------------
// Flash attention, causal — r18 structure (best: 129us): 1 wave/block,
// swapped QK^T lane-local softmax (exp2 domain, defer-max), vectorized PV
// via swizzled VT staging, grid balance, s_setprio.
// Grid: x = 64, y = 64 (b*h); 1 wave/block; LDS 12 KB.
// ---------------------------------------------------------------------------
__global__ __launch_bounds__(64) void flash_attn(
    const u16* __restrict__ Qg, const u16* __restrict__ Kg,
    const u16* __restrict__ VTg, u16* __restrict__ Og)
{
    __shared__ __align__(16) u16 Vsh[64 * 64];   // VT tile, swizzled
    __shared__ __align__(16) u16 Psh[32 * 64];

    const int lane = threadIdx.x;       // 0..63
    const int ln   = lane & 15;
    const int qd   = lane >> 4;
    const int psw  = (ln & 7) << 3;     // P swizzle (u16 elems)

    const int bh = blockIdx.y;
    const int qw = (63 - (int)blockIdx.x + bh) & 63;   // balance fix (r11)
    const int b  = bh >> 4;
    const int h  = bh & 15;
    const int h0 = h * 64;
    const size_t rowBase = (size_t)b * SEQ * D_MODEL;
    const int qw0 = qw * 32;
    const int ktMax = qw >> 1;          // last K-tile (only one needing mask)

    // VT staging source coords (dest is linear lane*16B per call)
    const int vdG = lane >> 3;          // 0..7 (= d&7 for every call)
    const int vsw = ((lane & 7) * 8) ^ (vdG << 3);
    const u16* vtRow0 = VTg + ((size_t)(bh * 64 + vdG)) * SEQ + vsw;

    const float SCL = 0.18033688011112042f;   // 0.125 * log2(e)

    // ---- Q fragments straight from global: B-frag [n=q=ln][k=qd*8+e] ----
    bf16x8 qf[2][2];
#pragma unroll
    for (int i = 0; i < 2; ++i)
#pragma unroll
        for (int ks = 0; ks < 2; ++ks)
            qf[i][ks] = *(const bf16x8*)(Qg + rowBase
                + (size_t)(qw0 + i * 16 + ln) * D_MODEL + h0 + ks * 32 + qd * 8);

    float m_run[2], l_run[2];
#pragma unroll
    for (int i = 0; i < 2; ++i) { m_run[i] = -30000.0f; l_run[i] = 0.f; }
    f32x4 oacc[2][4] = {};

    for (int kt = 0; kt <= ktMax; ++kt) {
        __syncthreads();                 // prev iter's Vsh/Psh reads done
        // ---- stage VT tile (64d x 64s) async; source col pre-swizzled ----
        {
            const u16* vbase = vtRow0 + kt * 64;
#pragma unroll
            for (int p = 0; p < 8; ++p)
                gload_lds16(vbase + (size_t)(p * 8) * SEQ, &Vsh[p * 512]);
        }

        // ---- S^T = K Q^T (K fragments straight from global) ----
        f32x4 sacc[4][2] = {};
#pragma unroll
        for (int ks = 0; ks < 2; ++ks) {
            bf16x8 kf[4];
#pragma unroll
            for (int j = 0; j < 4; ++j)
                kf[j] = *(const bf16x8*)(Kg + rowBase
                    + (size_t)(kt * 64 + j * 16 + ln) * D_MODEL + h0 + ks * 32 + qd * 8);
            __builtin_amdgcn_s_setprio(1);
#pragma unroll
            for (int j = 0; j < 4; ++j)
#pragma unroll
                for (int i = 0; i < 2; ++i)
                    sacc[j][i] = __builtin_amdgcn_mfma_f32_16x16x32_bf16(
                        kf[j], qf[i][ks], sacc[j][i], 0, 0, 0);
            __builtin_amdgcn_s_setprio(0);
        }

        // ---- scale to log2 domain (+ mask on the diagonal tile only) ----
        if (kt == ktMax) {
#pragma unroll
            for (int j = 0; j < 4; ++j)
#pragma unroll
                for (int r = 0; r < 4; ++r) {
                    const int kpos = kt * 64 + j * 16 + qd * 4 + r;
#pragma unroll
                    for (int i = 0; i < 2; ++i) {
                        const int qpos = qw0 + i * 16 + ln;
                        float s = sacc[j][i][r] * SCL;
                        sacc[j][i][r] = (kpos > qpos) ? -30000.0f : s;
                    }
                }
        } else {
#pragma unroll
            for (int j = 0; j < 4; ++j)
#pragma unroll
                for (int i = 0; i < 2; ++i)
#pragma unroll
                    for (int r = 0; r < 4; ++r)
                        sacc[j][i][r] *= SCL;
        }

        // ---- online softmax (log2 domain, lane-local) ----
        float mx[2];
#pragma unroll
        for (int i = 0; i < 2; ++i) {
            float m0 = sacc[0][i][0];
#pragma unroll
            for (int j = 0; j < 4; ++j)
#pragma unroll
                for (int r = 0; r < 4; ++r) m0 = fmaxf(m0, sacc[j][i][r]);
            m0 = fmaxf(m0, __shfl_xor(m0, 16));
            m0 = fmaxf(m0, __shfl_xor(m0, 32));
            mx[i] = m0;
        }

        // defer-max: skip rescale when max growth <= 8 (p <= 2^8)
        const bool grow = !(__all((mx[0] <= m_run[0] + 8.f) &&
                                  (mx[1] <= m_run[1] + 8.f)));
        if (grow) {
#pragma unroll
            for (int i = 0; i < 2; ++i) {
                const float mo = m_run[i];
                const float mn = fmaxf(mo, mx[i]);
                const float alpha = EXP2_FAST(mo - mn);
                m_run[i] = mn;
                l_run[i] *= alpha;
#pragma unroll
                for (int r = 0; r < 4; ++r) {
                    const float ar = __shfl(alpha, qd * 4 + r);
#pragma unroll
                    for (int j = 0; j < 4; ++j) oacc[i][j][r] *= ar;
                }
            }
        }

#pragma unroll
        for (int i = 0; i < 2; ++i) {
            const float mn = m_run[i];
            float rs = 0.f;
#pragma unroll
            for (int j = 0; j < 4; ++j) {
                u16 tp[4];
#pragma unroll
                for (int r = 0; r < 4; ++r) {
                    float p = EXP2_FAST(sacc[j][i][r] - mn);
                    rs += p;
                    tp[r] = f2bf_trunc(p);
                }
                uint2 w;
                w.x = (uint32_t)tp[0] | ((uint32_t)tp[1] << 16);
                w.y = (uint32_t)tp[2] | ((uint32_t)tp[3] << 16);
                *(uint2*)&Psh[(i * 16 + ln) * 64 + ((j * 16 + qd * 4) ^ psw)] = w;
            }
            rs += __shfl_xor(rs, 16);
            rs += __shfl_xor(rs, 32);
            l_run[i] += rs;
        }

        __syncthreads();                 // VT staged (vmcnt) + P visible

        // ---- O += P V : all-vector LDS reads ----
#pragma unroll
        for (int ks = 0; ks < 2; ++ks) {
            bf16x8 pa[2];                // A-frags of P: row = q = i*16+ln
#pragma unroll
            for (int i = 0; i < 2; ++i)
                pa[i] = *(const bf16x8*)&Psh[(i * 16 + ln) * 64
                                             + ((ks * 32 + qd * 8) ^ psw)];
            __builtin_amdgcn_s_setprio(1);
#pragma unroll
            for (int j = 0; j < 4; ++j) {
                const int d = j * 16 + ln;
                const bf16x8 vb = *(const bf16x8*)&Vsh[d * 64
                    + ((ks * 32 + qd * 8) ^ ((ln & 7) << 3))];
#pragma unroll
                for (int i = 0; i < 2; ++i)
                    oacc[i][j] = __builtin_amdgcn_mfma_f32_16x16x32_bf16(
                        pa[i], vb, oacc[i][j], 0, 0, 0);
            }
            __builtin_amdgcn_s_setprio(0);
        }
    }

    // ---- epilogue: O / l  (l lives at lane ln'=qd*4+r, shuffle it in) ----
#pragma unroll
    for (int i = 0; i < 2; ++i)
#pragma unroll
        for (int r = 0; r < 4; ++r) {
            const float lr = __shfl(l_run[i], qd * 4 + r);
            const float inv = 1.f / lr;
            const int qrow = qw0 + i * 16 + qd * 4 + r;
            u16* orow = Og + rowBase + (size_t)qrow * D_MODEL + h0 + ln;
#pragma unroll
            for (int j = 0; j < 4; ++j)
                orow[j * 16] = f2bf(oacc[i][j][r] * inv);
        }
}

// ---------------------------------------------------------------------------
static inline bool ranges_overlap(const void* a, size_t an, const void* b, size_t bn) {
    uintptr_t x0 = (uintptr_t)a, x1 = x0 + an;
    uintptr_t y0 = (uintptr_t)b, y1 = y0 + bn;
    return x0 < y1 && y0 < x1;
}

extern "C" void kernel_launch(void* const* d_in, const int* in_sizes, int n_in,
                              void* d_out, int out_size, void* d_ws, size_t ws_size,
                              hipStream_t stream)
{
    int e = 0;
    const int expect[9] = { 8388608, 1048576, 1024, 1048576, 1024,
                            1048576, 1024, 1048576, 1024 };
    if (n_in != 9) e = 59;
    if (!e) for (int i = 0; i < 9; ++i)
        if (in_sizes[i] != expect[i]) { e = 60 + i; break; }
    if (!e && out_size != (int)NXE) e = 53;
    if (!e && ranges_overlap(d_ws, ws_size, d_out, (size_t)out_size * 4)) e = 55;

    const size_t NX = NXE;
    const size_t NW = (size_t)D_MODEL * D_MODEL;
    const size_t NB = D_MODEL;

    // ws need: flag(64) + 4 weights + 4 biases + K + V = 40.0 MB (proven safe r7/r8).
    const size_t need = (64 + 4 * NW + 4 * NB + 2 * NX) * 2;
    if (!e && ws_size < need) e = 50;
    if (e) { diag_write<<<2048, 256, 0, stream>>>((float*)d_out, ldexpf(1.0f, e)); return; }

    // ws layout (u16 elems): flag | Wq Wk Wv Wo | bq bk bv bo | K | V
    u16* ws   = (u16*)d_ws;
    int* flag = (int*)ws;
    u16* Wqb  = ws + 64;
    u16* Wkb  = Wqb + NW;
    u16* Wvb  = Wkb + NW;
    u16* Wob  = Wvb + NW;
    u16* bqb  = Wob + NW;
    u16* bkb  = bqb + NB;
    u16* bvb  = bkb + NB;
    u16* bob  = bvb + NB;
    u16* Kw   = bob + NB;
    u16* Vw   = Kw  + NX;

    // Region lifetimes:
    //   d_out lower 16MB: xb (dead after gemm_qkv) -> VT (dead after flash)
    //   d_out upper 16MB: Qw (dead after flash)
    //   ws Vw: V (dead after transpose_v) -> Ow (attention output)
    //   gemm_final reads Ow (ws), writes fp32 DIRECTLY to d_out (no memcpy).
    u16* xb  = (u16*)d_out;          // x_bf16; dead after QKV gemm
    u16* Qw  = xb + NX;              // Q plane (upper half)
    u16* VTw = xb;                   // V^T reuses lower half
    u16* Ow  = Vw;                   // attention out over dead V plane

    detect_dtype<<<1, 256, 0, stream>>>((const u16*)d_in[0], flag);

    CvtArgs ca;
    const void* srcs[9] = { d_in[0], d_in[1], d_in[3], d_in[5], d_in[7],
                            d_in[2], d_in[4], d_in[6], d_in[8] };
    u16* dsts[9] = { xb, Wqb, Wkb, Wvb, Wob, bqb, bkb, bvb, bob };
    int  ns[9]   = { (int)NX, (int)NW, (int)NW, (int)NW, (int)NW,
                     (int)NB, (int)NB, (int)NB, (int)NB };
    for (int i = 0; i < 9; ++i) { ca.src[i] = srcs[i]; ca.dst[i] = dsts[i]; ca.n[i] = ns[i]; }
    cvt_all<<<dim3((unsigned)((NX + 2047) / 2048), 9), 256, 0, stream>>>(ca, flag);

    gemm_qkv<<<dim3(MTOT / 128, D_MODEL / 128, 3), 256, 0, stream>>>(
        xb, Wqb, Wkb, Wvb, bqb, bkb, bvb, Qw, Kw, Vw, MTOT, D_MODEL, D_MODEL);

    transpose_v<<<dim3(SEQ / 64, BATCH * NHEAD), 256, 0, stream>>>(Vw, VTw);

    flash_attn<<<dim3(SEQ / 32, BATCH * NHEAD), 64, 0, stream>>>(Qw, Kw, VTw, Ow);

    gemm_final_f32<<<dim3(MTOT / 128, D_MODEL / 128), 256, 0, stream>>>(
        Ow, Wob, bob, (float*)d_out, MTOT, D_MODEL, D_MODEL);
}

// Round 12
// 319.277 us; speedup vs baseline: 1.1753x; 1.0105x over previous
//
#include <hip/hip_runtime.h>
#include <cstdint>
#include <cmath>

typedef unsigned short u16;
typedef __attribute__((ext_vector_type(4))) float f32x4;
typedef __attribute__((ext_vector_type(8))) short bf16x8;

#define D_MODEL 1024
#define SEQ     2048
#define BATCH   4
#define NHEAD   16
#define MTOT    (BATCH*SEQ)      /* 8192 rows */
#define NXE     ((size_t)MTOT * D_MODEL)   /* 8,388,608 elems per plane */

static_assert(sizeof(bf16x8) == 16, "frag size");

__device__ __forceinline__ float bf2f(u16 u) {
    union { uint32_t i; float f; } v; v.i = ((uint32_t)u) << 16; return v.f;
}
__device__ __forceinline__ u16 f2bf(float x) {
    union { float f; uint32_t i; } v; v.f = x;
    uint32_t r = (v.i + 0x7FFFu + ((v.i >> 16) & 1u)) >> 16;   // RNE
    return (u16)r;
}
__device__ __forceinline__ u16 f2bf_trunc(float x) {          // cheap: P only
    union { float f; uint32_t i; } v; v.f = x;
    return (u16)(v.i >> 16);
}

// exp2 that lowers to a bare v_exp_f32 (HIP has no __exp2f; glibc macro clash)
#if defined(__has_builtin)
#if __has_builtin(__builtin_amdgcn_exp2f)
#define EXP2_FAST(x) __builtin_amdgcn_exp2f(x)
#endif
#endif
#ifndef EXP2_FAST
#define EXP2_FAST(x) exp2f(x)
#endif

typedef const __attribute__((address_space(1))) void* gptr_t;
typedef __attribute__((address_space(3))) void* sptr_t;
__device__ __forceinline__ void gload_lds16(const void* g, void* l) {
    __builtin_amdgcn_global_load_lds((gptr_t)g, (sptr_t)l, 16, 0, 0);
}

// extract u16 element e (compile-time const after unroll) from a uint4
__device__ __forceinline__ u16 u4get(const uint4& v, int e) {
    const uint32_t w = ((e >> 1) == 0) ? v.x : ((e >> 1) == 1) ? v.y
                     : ((e >> 1) == 2) ? v.z : v.w;
    return (u16)((e & 1) ? (w >> 16) : (w & 0xFFFFu));
}

// ---------------------------------------------------------------------------
// Precondition-failure flood: d_out is fp32; absmax report encodes 2^e.
// ---------------------------------------------------------------------------
__global__ __launch_bounds__(256) void diag_write(float* __restrict__ out, float v) {
    size_t i = (size_t)blockIdx.x * 256 + threadIdx.x;
    for (; i < NXE; i += (size_t)gridDim.x * 256) out[i] = v;
}

// ---------------------------------------------------------------------------
// Dtype sniffer (validated r3/r5/r6: inputs are fp32 -> flag=0).
// ---------------------------------------------------------------------------
__global__ void detect_dtype(const u16* __restrict__ x, int* __restrict__ flag) {
    __shared__ int cnt;
    if (threadIdx.x == 0) cnt = 0;
    __syncthreads();
    int c = 0;
#pragma unroll
    for (int k = 0; k < 16; ++k) {
        u16 e = x[2 * (threadIdx.x * 16 + k)];
        int ex = (e >> 7) & 0xFF;
        if (e == 0 || (ex >= 100 && ex <= 140)) ++c;
    }
    atomicAdd(&cnt, c);
    __syncthreads();
    if (threadIdx.x == 0) *flag = (cnt >= 3500) ? 1 : 0;
}

// ---------------------------------------------------------------------------
// Normalize inputs to bf16 planes (fp32 -> RNE downconvert; bf16 -> copy).
// ---------------------------------------------------------------------------
struct CvtArgs { const void* src[9]; u16* dst[9]; int n[9]; };

__global__ __launch_bounds__(256) void cvt_all(CvtArgs a, const int* __restrict__ flag) {
    const int seg = blockIdx.y;
    const int n = a.n[seg];
    const int i = (blockIdx.x * 256 + threadIdx.x) * 8;
    if (i >= n) return;
    u16* d = a.dst[seg] + i;
    if (*flag) {
        *(uint4*)d = *(const uint4*)((const u16*)a.src[seg] + i);
    } else {
        const float* s = (const float*)a.src[seg] + i;
        u16 tmp[8];
#pragma unroll
        for (int k = 0; k < 8; ++k) tmp[k] = f2bf(s[k]);
        *(uint4*)d = *(uint4*)tmp;
    }
}

// ---------------------------------------------------------------------------
// MFMA GEMM — round 21: r20 dbuf structure + T2 BANK-CONFLICT FIX.
//   Old fragment read As[row*32 + qd*8]: b128 bank-group = (4*row+qd) mod 8
//   spans only {qd, qd+4} over 16 lanes -> 8-WAY conflict (m136: 2.94x),
//   ~180 extra cyc per K-step on 8 ds_read_b128.
//   Fix (m173 pattern, LDS dest of global_load_lds must stay linear):
//   pre-swizzle the GLOBAL source chunk with chunk ^= (row>>1)&3 and read
//   with the same XOR.  Read group becomes (4*row + qd^((row>>1)&3)) mod 8
//   -> all 8 groups over row mod 8 -> 2-way = free (m136: 1.02x).
//   (row>>1)&3 = (ln>>1)&3 on reads / (t>>3)&3 on staging (lane-uniform);
//   8-u16 chunks = the 16B load granule, so coalescing is preserved and
//   the arithmetic is bit-identical.
// ---------------------------------------------------------------------------
template <typename OutT>
__device__ __forceinline__ void gemm_body(
    const u16* __restrict__ A, const u16* __restrict__ W,
    const u16* __restrict__ bias, OutT* __restrict__ C,
    int M, int N, int K)
{
    __shared__ __align__(16) u16 As[2][128 * 32];
    __shared__ __align__(16) u16 Bs[2][128 * 32];

    const int t    = threadIdx.x;
    const int wave = t >> 6;
    const int ln   = t & 15;
    const int qd   = (t >> 4) & 3;
    const int m0   = blockIdx.x * 128;
    const int n0   = blockIdx.y * 128;
    const int wm   = (wave >> 1) * 64;
    const int wn   = (wave & 1) * 64;

    const int srow = t >> 2;
    const int scol = ((t & 3) ^ ((t >> 3) & 3)) * 8;    // pre-swizzled source chunk
    const u16* gA = A + (size_t)(m0 + srow) * K + scol;
    const u16* gB = W + (size_t)(n0 + srow) * K + scol;

    const int ca = (qd ^ ((ln >> 1) & 3)) * 8;          // swizzled read chunk

    f32x4 acc[4][4] = {};

    // prologue: stage k0 = 0 into buffer 0
    {
        u16* lA = &As[0][wave * 512];
        u16* lB = &Bs[0][wave * 512];
        gload_lds16(gA,                   lA);
        gload_lds16(gA + (size_t)64 * K,  lA + 2048);
        gload_lds16(gB,                   lB);
        gload_lds16(gB + (size_t)64 * K,  lB + 2048);
    }
    __syncthreads();               // vmcnt(0) drained -> buf0 ready

    int cur = 0;
    for (int k0 = 0; k0 < K; k0 += 32) {
        // ---- stage NEXT tile into the other buffer (flies under compute) ----
        if (k0 + 32 < K) {
            u16* lA = &As[cur ^ 1][wave * 512];
            u16* lB = &Bs[cur ^ 1][wave * 512];
            gload_lds16(gA + k0 + 32,                   lA);
            gload_lds16(gA + (size_t)64 * K + k0 + 32,  lA + 2048);
            gload_lds16(gB + k0 + 32,                   lB);
            gload_lds16(gB + (size_t)64 * K + k0 + 32,  lB + 2048);
        }

        // ---- compute current tile (conflict-free swizzled reads) ----
        bf16x8 af[4], bfr[4];
#pragma unroll
        for (int i = 0; i < 4; ++i)
            af[i] = *(const bf16x8*)&As[cur][(wm + i * 16 + ln) * 32 + ca];
#pragma unroll
        for (int j = 0; j < 4; ++j)
            bfr[j] = *(const bf16x8*)&Bs[cur][(wn + j * 16 + ln) * 32 + ca];
#pragma unroll
        for (int i = 0; i < 4; ++i)
#pragma unroll
            for (int j = 0; j < 4; ++j)
                acc[i][j] = __builtin_amdgcn_mfma_f32_16x16x32_bf16(
                    af[i], bfr[j], acc[i][j], 0, 0, 0);

        __syncthreads();           // next loads landed + our ds_reads done
        cur ^= 1;
    }

    float bv[4];
#pragma unroll
    for (int j = 0; j < 4; ++j) bv[j] = bf2f(bias[n0 + wn + j * 16 + ln]);

#pragma unroll
    for (int i = 0; i < 4; ++i)
#pragma unroll
        for (int r = 0; r < 4; ++r) {
            int row = m0 + wm + i * 16 + qd * 4 + r;
            OutT* crow = C + (size_t)row * N + n0 + wn + ln;
#pragma unroll
            for (int j = 0; j < 4; ++j) {
                float v = acc[i][j][r] + bv[j];
                if constexpr (sizeof(OutT) == 2) crow[j * 16] = f2bf(v);
                else                             crow[j * 16] = v;
            }
        }
}

__global__ __launch_bounds__(256) void gemm_qkv(
    const u16* __restrict__ A,
    const u16* __restrict__ W0, const u16* __restrict__ W1, const u16* __restrict__ W2,
    const u16* __restrict__ b0, const u16* __restrict__ b1, const u16* __restrict__ b2,
    u16* __restrict__ C0, u16* __restrict__ C1, u16* __restrict__ C2,
    int M, int N, int K)
{
    const u16* W; const u16* bias; u16* C;
    if (blockIdx.z == 0)      { W = W0; bias = b0; C = C0; }
    else if (blockIdx.z == 1) { W = W1; bias = b1; C = C1; }
    else                      { W = W2; bias = b2; C = C2; }
    gemm_body<u16>(A, W, bias, C, M, N, K);
}

__global__ __launch_bounds__(256) void gemm_final_f32(
    const u16* __restrict__ A, const u16* __restrict__ W,
    const u16* __restrict__ bias, float* __restrict__ C, int M, int N, int K)
{
    gemm_body<float>(A, W, bias, C, M, N, K);
}

// ---------------------------------------------------------------------------
// V transpose: V[b*S+s][h*64+d]  ->  VT[(bh*64+d)][s]   (per-head d-major).
// 64x64 tiles through LDS; ~32 MB total traffic (~6 us). Proven correct (r12).
// ---------------------------------------------------------------------------
__global__ __launch_bounds__(256) void transpose_v(
    const u16* __restrict__ V, u16* __restrict__ VT)
{
    __shared__ u16 T[64][72];           // +8 pad: 144 B row stride (16B-aligned)
    const int st = blockIdx.x;          // s-tile (0..31)
    const int bh = blockIdx.y;          // 0..63
    const int b  = bh >> 4;
    const int h  = bh & 15;
    const int t  = threadIdx.x;

    const int sr = t >> 2;              // local s row 0..63
    const int dc = (t & 3) * 16;        // d chunk 0,16,32,48
    const u16* src = V + ((size_t)b * SEQ + st * 64 + sr) * D_MODEL + h * 64 + dc;
    const uint4 a0 = *(const uint4*)src;
    const uint4 a1 = *(const uint4*)(src + 8);
#pragma unroll
    for (int e = 0; e < 8; ++e) T[dc + e][sr]     = u4get(a0, e);
#pragma unroll
    for (int e = 0; e < 8; ++e) T[dc + 8 + e][sr] = u4get(a1, e);
    __syncthreads();

    const int d  = t >> 2;              // 0..63
    const int sc = (t & 3) * 16;        // 0,16,32,48
    u16* dst = VT + ((size_t)bh * 64 + d) * SEQ + st * 64 + sc;
    *(uint4*)dst       = *(const uint4*)&T[d][sc];
    *(uint4*)(dst + 8) = *(const uint4*)&T[d][sc + 8];
}

// ---------------------------------------------------------------------------
// Flash attention, causal — r18 structure (best: 129us): 1 wave/block,
// swapped QK^T lane-local softmax (exp2 domain, defer-max), vectorized PV
// via swizzled VT staging, grid balance, s_setprio.
// Grid: x = 64, y = 64 (b*h); 1 wave/block; LDS 12 KB.
// ---------------------------------------------------------------------------
__global__ __launch_bounds__(64) void flash_attn(
    const u16* __restrict__ Qg, const u16* __restrict__ Kg,
    const u16* __restrict__ VTg, u16* __restrict__ Og)
{
    __shared__ __align__(16) u16 Vsh[64 * 64];   // VT tile, swizzled
    __shared__ __align__(16) u16 Psh[32 * 64];

    const int lane = threadIdx.x;       // 0..63
    const int ln   = lane & 15;
    const int qd   = lane >> 4;
    const int psw  = (ln & 7) << 3;     // P swizzle (u16 elems)

    const int bh = blockIdx.y;
    const int qw = (63 - (int)blockIdx.x + bh) & 63;   // balance fix (r11)
    const int b  = bh >> 4;
    const int h  = bh & 15;
    const int h0 = h * 64;
    const size_t rowBase = (size_t)b * SEQ * D_MODEL;
    const int qw0 = qw * 32;
    const int ktMax = qw >> 1;          // last K-tile (only one needing mask)

    // VT staging source coords (dest is linear lane*16B per call)
    const int vdG = lane >> 3;          // 0..7 (= d&7 for every call)
    const int vsw = ((lane & 7) * 8) ^ (vdG << 3);
    const u16* vtRow0 = VTg + ((size_t)(bh * 64 + vdG)) * SEQ + vsw;

    const float SCL = 0.18033688011112042f;   // 0.125 * log2(e)

    // ---- Q fragments straight from global: B-frag [n=q=ln][k=qd*8+e] ----
    bf16x8 qf[2][2];
#pragma unroll
    for (int i = 0; i < 2; ++i)
#pragma unroll
        for (int ks = 0; ks < 2; ++ks)
            qf[i][ks] = *(const bf16x8*)(Qg + rowBase
                + (size_t)(qw0 + i * 16 + ln) * D_MODEL + h0 + ks * 32 + qd * 8);

    float m_run[2], l_run[2];
#pragma unroll
    for (int i = 0; i < 2; ++i) { m_run[i] = -30000.0f; l_run[i] = 0.f; }
    f32x4 oacc[2][4] = {};

    for (int kt = 0; kt <= ktMax; ++kt) {
        __syncthreads();                 // prev iter's Vsh/Psh reads done
        // ---- stage VT tile (64d x 64s) async; source col pre-swizzled ----
        {
            const u16* vbase = vtRow0 + kt * 64;
#pragma unroll
            for (int p = 0; p < 8; ++p)
                gload_lds16(vbase + (size_t)(p * 8) * SEQ, &Vsh[p * 512]);
        }

        // ---- S^T = K Q^T (K fragments straight from global) ----
        f32x4 sacc[4][2] = {};
#pragma unroll
        for (int ks = 0; ks < 2; ++ks) {
            bf16x8 kf[4];
#pragma unroll
            for (int j = 0; j < 4; ++j)
                kf[j] = *(const bf16x8*)(Kg + rowBase
                    + (size_t)(kt * 64 + j * 16 + ln) * D_MODEL + h0 + ks * 32 + qd * 8);
            __builtin_amdgcn_s_setprio(1);
#pragma unroll
            for (int j = 0; j < 4; ++j)
#pragma unroll
                for (int i = 0; i < 2; ++i)
                    sacc[j][i] = __builtin_amdgcn_mfma_f32_16x16x32_bf16(
                        kf[j], qf[i][ks], sacc[j][i], 0, 0, 0);
            __builtin_amdgcn_s_setprio(0);
        }

        // ---- scale to log2 domain (+ mask on the diagonal tile only) ----
        if (kt == ktMax) {
#pragma unroll
            for (int j = 0; j < 4; ++j)
#pragma unroll
                for (int r = 0; r < 4; ++r) {
                    const int kpos = kt * 64 + j * 16 + qd * 4 + r;
#pragma unroll
                    for (int i = 0; i < 2; ++i) {
                        const int qpos = qw0 + i * 16 + ln;
                        float s = sacc[j][i][r] * SCL;
                        sacc[j][i][r] = (kpos > qpos) ? -30000.0f : s;
                    }
                }
        } else {
#pragma unroll
            for (int j = 0; j < 4; ++j)
#pragma unroll
                for (int i = 0; i < 2; ++i)
#pragma unroll
                    for (int r = 0; r < 4; ++r)
                        sacc[j][i][r] *= SCL;
        }

        // ---- online softmax (log2 domain, lane-local) ----
        float mx[2];
#pragma unroll
        for (int i = 0; i < 2; ++i) {
            float m0 = sacc[0][i][0];
#pragma unroll
            for (int j = 0; j < 4; ++j)
#pragma unroll
                for (int r = 0; r < 4; ++r) m0 = fmaxf(m0, sacc[j][i][r]);
            m0 = fmaxf(m0, __shfl_xor(m0, 16));
            m0 = fmaxf(m0, __shfl_xor(m0, 32));
            mx[i] = m0;
        }

        // defer-max: skip rescale when max growth <= 8 (p <= 2^8)
        const bool grow = !(__all((mx[0] <= m_run[0] + 8.f) &&
                                  (mx[1] <= m_run[1] + 8.f)));
        if (grow) {
#pragma unroll
            for (int i = 0; i < 2; ++i) {
                const float mo = m_run[i];
                const float mn = fmaxf(mo, mx[i]);
                const float alpha = EXP2_FAST(mo - mn);
                m_run[i] = mn;
                l_run[i] *= alpha;
#pragma unroll
                for (int r = 0; r < 4; ++r) {
                    const float ar = __shfl(alpha, qd * 4 + r);
#pragma unroll
                    for (int j = 0; j < 4; ++j) oacc[i][j][r] *= ar;
                }
            }
        }

#pragma unroll
        for (int i = 0; i < 2; ++i) {
            const float mn = m_run[i];
            float rs = 0.f;
#pragma unroll
            for (int j = 0; j < 4; ++j) {
                u16 tp[4];
#pragma unroll
                for (int r = 0; r < 4; ++r) {
                    float p = EXP2_FAST(sacc[j][i][r] - mn);
                    rs += p;
                    tp[r] = f2bf_trunc(p);
                }
                uint2 w;
                w.x = (uint32_t)tp[0] | ((uint32_t)tp[1] << 16);
                w.y = (uint32_t)tp[2] | ((uint32_t)tp[3] << 16);
                *(uint2*)&Psh[(i * 16 + ln) * 64 + ((j * 16 + qd * 4) ^ psw)] = w;
            }
            rs += __shfl_xor(rs, 16);
            rs += __shfl_xor(rs, 32);
            l_run[i] += rs;
        }

        __syncthreads();                 // VT staged (vmcnt) + P visible

        // ---- O += P V : all-vector LDS reads ----
#pragma unroll
        for (int ks = 0; ks < 2; ++ks) {
            bf16x8 pa[2];                // A-frags of P: row = q = i*16+ln
#pragma unroll
            for (int i = 0; i < 2; ++i)
                pa[i] = *(const bf16x8*)&Psh[(i * 16 + ln) * 64
                                             + ((ks * 32 + qd * 8) ^ psw)];
            __builtin_amdgcn_s_setprio(1);
#pragma unroll
            for (int j = 0; j < 4; ++j) {
                const int d = j * 16 + ln;
                const bf16x8 vb = *(const bf16x8*)&Vsh[d * 64
                    + ((ks * 32 + qd * 8) ^ ((ln & 7) << 3))];
#pragma unroll
                for (int i = 0; i < 2; ++i)
                    oacc[i][j] = __builtin_amdgcn_mfma_f32_16x16x32_bf16(
                        pa[i], vb, oacc[i][j], 0, 0, 0);
            }
            __builtin_amdgcn_s_setprio(0);
        }
    }

    // ---- epilogue: O / l  (l lives at lane ln'=qd*4+r, shuffle it in) ----
#pragma unroll
    for (int i = 0; i < 2; ++i)
#pragma unroll
        for (int r = 0; r < 4; ++r) {
            const float lr = __shfl(l_run[i], qd * 4 + r);
            const float inv = 1.f / lr;
            const int qrow = qw0 + i * 16 + qd * 4 + r;
            u16* orow = Og + rowBase + (size_t)qrow * D_MODEL + h0 + ln;
#pragma unroll
            for (int j = 0; j < 4; ++j)
                orow[j * 16] = f2bf(oacc[i][j][r] * inv);
        }
}

// ---------------------------------------------------------------------------
static inline bool ranges_overlap(const void* a, size_t an, const void* b, size_t bn) {
    uintptr_t x0 = (uintptr_t)a, x1 = x0 + an;
    uintptr_t y0 = (uintptr_t)b, y1 = y0 + bn;
    return x0 < y1 && y0 < x1;
}

extern "C" void kernel_launch(void* const* d_in, const int* in_sizes, int n_in,
                              void* d_out, int out_size, void* d_ws, size_t ws_size,
                              hipStream_t stream)
{
    int e = 0;
    const int expect[9] = { 8388608, 1048576, 1024, 1048576, 1024,
                            1048576, 1024, 1048576, 1024 };
    if (n_in != 9) e = 59;
    if (!e) for (int i = 0; i < 9; ++i)
        if (in_sizes[i] != expect[i]) { e = 60 + i; break; }
    if (!e && out_size != (int)NXE) e = 53;
    if (!e && ranges_overlap(d_ws, ws_size, d_out, (size_t)out_size * 4)) e = 55;

    const size_t NX = NXE;
    const size_t NW = (size_t)D_MODEL * D_MODEL;
    const size_t NB = D_MODEL;

    // ws need: flag(64) + 4 weights + 4 biases + K + V = 40.0 MB (proven safe r7/r8).
    const size_t need = (64 + 4 * NW + 4 * NB + 2 * NX) * 2;
    if (!e && ws_size < need) e = 50;
    if (e) { diag_write<<<2048, 256, 0, stream>>>((float*)d_out, ldexpf(1.0f, e)); return; }

    // ws layout (u16 elems): flag | Wq Wk Wv Wo | bq bk bv bo | K | V
    u16* ws   = (u16*)d_ws;
    int* flag = (int*)ws;
    u16* Wqb  = ws + 64;
    u16* Wkb  = Wqb + NW;
    u16* Wvb  = Wkb + NW;
    u16* Wob  = Wvb + NW;
    u16* bqb  = Wob + NW;
    u16* bkb  = bqb + NB;
    u16* bvb  = bkb + NB;
    u16* bob  = bvb + NB;
    u16* Kw   = bob + NB;
    u16* Vw   = Kw  + NX;

    // Region lifetimes:
    //   d_out lower 16MB: xb (dead after gemm_qkv) -> VT (dead after flash)
    //   d_out upper 16MB: Qw (dead after flash)
    //   ws Vw: V (dead after transpose_v) -> Ow (attention output)
    //   gemm_final reads Ow (ws), writes fp32 DIRECTLY to d_out (no memcpy).
    u16* xb  = (u16*)d_out;          // x_bf16; dead after QKV gemm
    u16* Qw  = xb + NX;              // Q plane (upper half)
    u16* VTw = xb;                   // V^T reuses lower half
    u16* Ow  = Vw;                   // attention out over dead V plane

    detect_dtype<<<1, 256, 0, stream>>>((const u16*)d_in[0], flag);

    CvtArgs ca;
    const void* srcs[9] = { d_in[0], d_in[1], d_in[3], d_in[5], d_in[7],
                            d_in[2], d_in[4], d_in[6], d_in[8] };
    u16* dsts[9] = { xb, Wqb, Wkb, Wvb, Wob, bqb, bkb, bvb, bob };
    int  ns[9]   = { (int)NX, (int)NW, (int)NW, (int)NW, (int)NW,
                     (int)NB, (int)NB, (int)NB, (int)NB };
    for (int i = 0; i < 9; ++i) { ca.src[i] = srcs[i]; ca.dst[i] = dsts[i]; ca.n[i] = ns[i]; }
    cvt_all<<<dim3((unsigned)((NX + 2047) / 2048), 9), 256, 0, stream>>>(ca, flag);

    gemm_qkv<<<dim3(MTOT / 128, D_MODEL / 128, 3), 256, 0, stream>>>(
        xb, Wqb, Wkb, Wvb, bqb, bkb, bvb, Qw, Kw, Vw, MTOT, D_MODEL, D_MODEL);

    transpose_v<<<dim3(SEQ / 64, BATCH * NHEAD), 256, 0, stream>>>(Vw, VTw);

    flash_attn<<<dim3(SEQ / 32, BATCH * NHEAD), 64, 0, stream>>>(Qw, Kw, VTw, Ow);

    gemm_final_f32<<<dim3(MTOT / 128, D_MODEL / 128), 256, 0, stream>>>(
        Ow, Wob, bob, (float*)d_out, MTOT, D_MODEL, D_MODEL);
}